// Round 1
// baseline (459.397 us; speedup 1.0000x reference)
//
#include <hip/hip_runtime.h>
#include <hip/hip_fp16.h>

// 2-layer GCN, pull-based CSR aggregation. fp32 math; h1 fp8-e4m3, z/h2 fp16.
// R16: hist/offsets/scatter/csr/gemm1 fused into ONE persistent kernel with
// device-scope grid barriers (grid sized by occupancy query -> co-resident).
// Rationale: unique HBM traffic ~70MB (~11us floor) vs 189us measured and all
// kernels <44us -> launch/serialization-bound, not BW-bound. Fusion removes
// 4 launch gaps; gemm1 tiles run concurrently with the (tiny) offsets phase;
// W1 converted to fp16-T once in global (L2-resident) instead of per-block
// LDS restaging, shrinking gemm LDS 68->34KB so 3-4 blocks/CU keep all
// phases parallel. Math order unchanged -> output bit-identical to R15.
// (R15: LDS counting-sort scatter; R14: agg1 2-wave split regressed; R10:
// stride-132 fp32 epilogue; R5/R6: no global atomics in CSR build.)

#define FDIM 128
#define CHUNK 2048   // edges per chunk; nchunks = ceil(E/CHUNK) must be <= 512

using half8   = __attribute__((ext_vector_type(8))) _Float16;
using float4v = __attribute__((ext_vector_type(4))) float;
using float2v = __attribute__((ext_vector_type(2))) float;

__device__ __forceinline__ float2v fp8x2_to_f32x2(unsigned short hv) {
    return __builtin_amdgcn_cvt_pk_f32_fp8((int)hv, false);
}

// Device-scope grid barrier. Correct because grid <= co-resident capacity
// (occupancy-query-sized) so every block is running. Cumulative single-cell
// count: target for barrier k is k*gridDim.x (monotonic -> no reset races).
__device__ __forceinline__ void grid_barrier(int* bar, int target) {
    __syncthreads();
    if (threadIdx.x == 0) {
        __threadfence();  // release all prior writes (device scope, cross-XCD)
        __hip_atomic_fetch_add(bar, 1, __ATOMIC_RELEASE, __HIP_MEMORY_SCOPE_AGENT);
        while (__hip_atomic_load(bar, __ATOMIC_ACQUIRE, __HIP_MEMORY_SCOPE_AGENT) < target)
            __builtin_amdgcn_s_sleep(2);
        __threadfence();
    }
    __syncthreads();
}

// Phases:
//  P0: per-chunk dst histogram (nchunks jobs) + W1 -> fp16-transposed (16 slices)
//  P1: per-bucket chunk-offset scan (nbk jobs)  ||  gemm1 MFMA tiles (nbt jobs)
//  P2: scatter with LDS counting sort (nchunks jobs)
//  P3: CSR finalize per bucket (nbk jobs)
__global__ void build_kernel(const float* __restrict__ x, const int* __restrict__ ei,
                             const float* __restrict__ W1,
                             int E, int N, int nchunks, int nbk, int nbt,
                             int* __restrict__ histT, int* __restrict__ tot,
                             unsigned* __restrict__ bkt, int* __restrict__ adj,
                             int* __restrict__ rowstart, float* __restrict__ dinv,
                             _Float16* __restrict__ Wt, unsigned char* __restrict__ h1,
                             int* __restrict__ bar) {
    __shared__ __align__(16) unsigned char smem[34816];
    const int nb = gridDim.x;
    const int t  = threadIdx.x;

    // ---------------- P0: histogram + W1 fp16 transpose --------------------
    for (int j = blockIdx.x; j < nchunks + 16; j += nb) {
        if (j < nchunks) {
            int* hist = (int*)smem;
            hist[t] = 0;
            __syncthreads();
            const int* dst = ei + E;
            int base = j * CHUNK;
#pragma unroll
            for (int k = 0; k < CHUNK / 256; ++k) {
                int e = base + k * 256 + t;
                if (e < E) atomicAdd(&hist[dst[e] >> 8], 1);
            }
            __syncthreads();
            if (t < nbk) histT[t * nchunks + j] = hist[t];
            __syncthreads();
        } else {
            // W1[k][n] (fp32) -> Wt[n][k] (fp16), 1024 elems per slice.
            int p = (j - nchunks) * 1024 + t;
#pragma unroll
            for (int k = 0; k < 4; ++k, p += 256) {
                int n = p >> 7, kk = p & 127;
                Wt[n * 128 + kk] = (_Float16)W1[kk * 128 + n];
            }
        }
    }
    grid_barrier(bar, 1 * nb);

    // ---------------- P1: offsets scan || gemm1 ----------------------------
    for (int j = blockIdx.x; j < nbk + nbt; j += nb) {
        if (j < nbk) {
            // exclusive scan of <=512 chunk counts; 2 slots/thread Hillis-Steele
            int* s = (int*)smem;
            __syncthreads();
            int* row = histT + (size_t)j * nchunks;
            int v0 = (t < nchunks) ? row[t] : 0;
            int v1 = (t + 256 < nchunks) ? row[t + 256] : 0;
            s[t] = v0;
            s[t + 256] = v1;
            __syncthreads();
            for (int off = 1; off < 512; off <<= 1) {
                int a  = (t >= off) ? s[t - off] : 0;
                int b2 = s[t + 256 - off];   // t+256 >= off always (off<=256)
                __syncthreads();
                s[t] += a;
                s[t + 256] += b2;
                __syncthreads();
            }
            if (t < nchunks) row[t] = s[t] - v0;                   // local excl offset
            if (t + 256 < nchunks) row[t + 256] = s[t + 256] - v1;
            if (t == 255) tot[j] = s[511];                         // bucket total
        } else {
            // ---- gemm1 tile: h1 = fp8(fp16(x) @ Wt^T), fp32 accum ----
            int tile = j - nbk;
            __syncthreads();   // guard smem reuse across jobs
            _Float16* Xs = (_Float16*)smem;   // 128 x 136 fp16 = 34816 B
            int i0 = tile * 128;
            for (int p = t; p < 128 * 32; p += 256) {
                int row = p >> 5;
                int col4 = (p & 31) * 4;
                int grow = i0 + row;
                float4 v = make_float4(0.f, 0.f, 0.f, 0.f);
                if (grow < N) v = *(const float4*)(x + (size_t)grow * FDIM + col4);
                _Float16* d = &Xs[row * 136 + col4];
                d[0] = (_Float16)v.x;
                d[1] = (_Float16)v.y;
                d[2] = (_Float16)v.z;
                d[3] = (_Float16)v.w;
            }
            __syncthreads();

            int lane = t & 63, w = t >> 6;
            int c = lane & 15, q = lane >> 4;
            int m0 = w * 32;

            float4v acc[2][8];
#pragma unroll
            for (int r = 0; r < 2; ++r)
#pragma unroll
                for (int nt = 0; nt < 8; ++nt) acc[r][nt] = (float4v)(0.f);

#pragma unroll
            for (int kk = 0; kk < 4; ++kk) {
                int k0 = kk * 32 + q * 8;
                half8 a0 = *(const half8*)&Xs[(m0 + c) * 136 + k0];
                half8 a1 = *(const half8*)&Xs[(m0 + 16 + c) * 136 + k0];
#pragma unroll
                for (int nt = 0; nt < 8; ++nt) {
                    half8 bv = *(const half8*)&Wt[(nt * 16 + c) * 128 + k0];  // L2-hit
                    acc[0][nt] = __builtin_amdgcn_mfma_f32_16x16x32_f16(a0, bv, acc[0][nt], 0, 0, 0);
                    acc[1][nt] = __builtin_amdgcn_mfma_f32_16x16x32_f16(a1, bv, acc[1][nt], 0, 0, 0);
                }
            }
            // epilogue in two 64-row half-tiles: T[64][132] fp32 = 33792 B fits
            float* T = (float*)smem;
#pragma unroll
            for (int half = 0; half < 2; ++half) {
                __syncthreads();
                if ((w >> 1) == half) {
#pragma unroll
                    for (int r = 0; r < 2; ++r)
#pragma unroll
                        for (int reg = 0; reg < 4; ++reg) {
                            int rl = (m0 & 63) + r * 16 + q * 4 + reg;
#pragma unroll
                            for (int nt = 0; nt < 8; ++nt)
                                T[rl * 132 + nt * 16 + c] = acc[r][nt][reg];
                        }
                }
                __syncthreads();
                for (int p = t; p < 64 * 32; p += 256) {
                    int row = p >> 5;
                    int col4 = (p & 31) * 4;
                    int grow = i0 + half * 64 + row;
                    if (grow < N) {
                        const float* src = &T[row * 132 + col4];
                        int lo = __builtin_amdgcn_cvt_pk_fp8_f32(src[0], src[1], 0, false);
                        int hi = __builtin_amdgcn_cvt_pk_fp8_f32(src[2], src[3], 0, false);
                        unsigned word = ((unsigned)lo & 0xFFFFu) | (((unsigned)hi & 0xFFFFu) << 16);
                        *(unsigned*)(h1 + (size_t)grow * 128 + col4) = word;
                    }
                }
            }
        }
    }
    grid_barrier(bar, 2 * nb);

    // ---------------- P2: scatter with in-LDS counting sort ----------------
    for (int j = blockIdx.x; j < nchunks; j += nb) {
        int* s        = (int*)smem;               // 256 ints
        int* delta    = (int*)(smem + 1024);      // 256 ints
        int* lcur     = (int*)(smem + 2048);      // 256 ints
        unsigned* buf = (unsigned*)(smem + 3072); // 2048 u32
        int* dst32    = (int*)(smem + 11264);     // 2048 ints
        __syncthreads();
        int v = (t < nbk) ? tot[t] : 0;
        s[t] = v;
        __syncthreads();
        for (int off = 1; off < 256; off <<= 1) {
            int tv = (t >= off) ? s[t - off] : 0;
            __syncthreads();
            s[t] += tv;
            __syncthreads();
        }
        int gbase = (t < nbk) ? (s[t] - v) + histT[t * nchunks + j] : 0;
        int lcnt = 0;
        if (t < nbk) {
            int cur_off = histT[t * nchunks + j];
            int nxt_off = (j + 1 < nchunks) ? histT[t * nchunks + j + 1] : tot[t];
            lcnt = nxt_off - cur_off;
        }
        __syncthreads();
        s[t] = lcnt;
        __syncthreads();
        for (int off = 1; off < 256; off <<= 1) {
            int tv = (t >= off) ? s[t - off] : 0;
            __syncthreads();
            s[t] += tv;
            __syncthreads();
        }
        int lofs = s[t] - lcnt;
        lcur[t] = lofs;
        delta[t] = gbase - lofs;
        __syncthreads();

        int base = j * CHUNK;
#pragma unroll
        for (int k = 0; k < CHUNK / 256; ++k) {
            int e = base + k * 256 + t;
            if (e < E) {
                int src = ei[e];
                int d = ei[E + e];
                int b = d >> 8;
                int pos = atomicAdd(&lcur[b], 1);   // LDS atomic
                buf[pos] = ((unsigned)(d & 255) << 24) | (unsigned)src;
                dst32[pos] = delta[b] + pos;
            }
        }
        __syncthreads();
        int cnt = min(CHUNK, E - base);
        for (int p = t; p < cnt; p += 256)
            bkt[dst32[p]] = buf[p];
    }
    grid_barrier(bar, 3 * nb);

    // ---------------- P3: CSR finalize per bucket --------------------------
    for (int j = blockIdx.x; j < nbk; j += nb) {
        int* sbuf = (int*)smem;
        int* hist = (int*)(smem + 1024);
        int* cur  = (int*)(smem + 2048);
        __syncthreads();
        int v = (t < nbk) ? tot[t] : 0;
        sbuf[t] = v;
        __syncthreads();
        for (int off = 1; off < 256; off <<= 1) {
            int tv = (t >= off) ? sbuf[t - off] : 0;
            __syncthreads();
            sbuf[t] += tv;
            __syncthreads();
        }
        int bb = sbuf[j] - tot[j];
        int nb_ = tot[j];
        __syncthreads();
        hist[t] = 0;
        __syncthreads();
        const unsigned* bk = bkt + bb;
        for (int e = t; e < nb_; e += 256) atomicAdd(&hist[bk[e] >> 24], 1);
        __syncthreads();
        int h_t = hist[t];
        sbuf[t] = h_t;
        __syncthreads();
        for (int off = 1; off < 256; off <<= 1) {
            int vv = (t >= off) ? sbuf[t - off] : 0;
            __syncthreads();
            sbuf[t] += vv;
            __syncthreads();
        }
        int excl_t = sbuf[t] - h_t;
        int node = j * 256 + t;
        if (node < N) {
            rowstart[node] = bb + excl_t;
            dinv[node] = rsqrtf((float)(h_t + 1));   // +1 self-loop
        }
        if (j == 0 && t == 0) rowstart[N] = E;
        cur[t] = excl_t;
        __syncthreads();
        for (int e = t; e < nb_; e += 256) {
            unsigned vv = bk[e];
            int pos = atomicAdd(&cur[vv >> 24], 1);   // LDS atomic
            adj[bb + pos] = (int)(vv & 0xFFFFFFu);    // src < 2^24
        }
    }
}

// z[i,:] = relu( dinv[i]*(sum_s h1[s,:]*dinv[s] + h1[i,:]*dinv[i]) + b1 ) + x[i,:]
// h1 fp8-e4m3, 128 B/row; lane = 2 feats; 8 gathers in flight. (R13 form.)
__global__ void agg1_kernel(const unsigned char* __restrict__ h1, const int* __restrict__ rowstart,
                            const int* __restrict__ adj, const float* __restrict__ dinv,
                            const float* __restrict__ x, const float* __restrict__ b1,
                            __half* __restrict__ z, int N) {
    int wave = threadIdx.x >> 6;
    int lane = threadIdx.x & 63;
    int i = blockIdx.x * 4 + wave;
    if (i >= N) return;
    int s0 = rowstart[i], s1 = rowstart[i + 1];
    float ax = 0.f, ay = 0.f;
    int n = s0;
    for (; n + 7 < s1; n += 8) {
        int s[8];
        float w[8];
        unsigned short hv[8];
#pragma unroll
        for (int q = 0; q < 8; ++q) s[q] = adj[n + q];
#pragma unroll
        for (int q = 0; q < 8; ++q) w[q] = dinv[s[q]];
#pragma unroll
        for (int q = 0; q < 8; ++q)
            hv[q] = *(const unsigned short*)(h1 + (size_t)s[q] * 128 + lane * 2);
#pragma unroll
        for (int q = 0; q < 8; ++q) {
            float2v f = fp8x2_to_f32x2(hv[q]);
            ax += f.x * w[q];
            ay += f.y * w[q];
        }
    }
    if (n + 3 < s1) {
        int s[4];
        float w[4];
        unsigned short hv[4];
#pragma unroll
        for (int q = 0; q < 4; ++q) s[q] = adj[n + q];
#pragma unroll
        for (int q = 0; q < 4; ++q) w[q] = dinv[s[q]];
#pragma unroll
        for (int q = 0; q < 4; ++q)
            hv[q] = *(const unsigned short*)(h1 + (size_t)s[q] * 128 + lane * 2);
#pragma unroll
        for (int q = 0; q < 4; ++q) {
            float2v f = fp8x2_to_f32x2(hv[q]);
            ax += f.x * w[q];
            ay += f.y * w[q];
        }
        n += 4;
    }
    for (; n < s1; ++n) {
        int sa = adj[n];
        float wa = dinv[sa];
        float2v f = fp8x2_to_f32x2(*(const unsigned short*)(h1 + (size_t)sa * 128 + lane * 2));
        ax += f.x * wa;
        ay += f.y * wa;
    }
    float di = dinv[i];
    float self = di * di;
    float2v hi = fp8x2_to_f32x2(*(const unsigned short*)(h1 + (size_t)i * 128 + lane * 2));
    ax = ax * di + hi.x * self;
    ay = ay * di + hi.y * self;
    float2 bb = ((const float2*)b1)[lane];
    float2 xi = ((const float2*)(x + (size_t)i * FDIM))[lane];
    float rx = fmaxf(ax + bb.x, 0.f) + xi.x;
    float ry = fmaxf(ay + bb.y, 0.f) + xi.y;
    ((__half2*)(z + (size_t)i * FDIM))[lane] = __floats2half2_rn(rx, ry);
}

// ---- MFMA GEMM2: h2 = z @ fp16(W2), fp32 accum, fp16 out (stride 40) ----
__launch_bounds__(256, 2)
__global__ void gemm2_mfma(const __half* __restrict__ z, const float* __restrict__ W2,
                           __half* __restrict__ h2, int N) {
    __shared__ __align__(16) unsigned char smem[49152];
    _Float16* Zs  = (_Float16*)smem;                 // 128*136*2 = 34816 B
    _Float16* W2t = (_Float16*)(smem + 34816);       // 48*136*2  = 13056 B
    int t = threadIdx.x;
    int i0 = blockIdx.x * 128;

    for (int p = t; p < 128 * 16; p += 256) {
        int row = p >> 4;
        int ck = (p & 15) * 8;
        int grow = i0 + row;
        half8 v = (half8)(_Float16)0;
        if (grow < N) v = *(const half8*)(z + (size_t)grow * FDIM + ck);
        *(half8*)&Zs[row * 136 + ck] = v;
    }
    for (int p = t; p < 48 * 128; p += 256) {
        int n = p >> 7;
        int k = p & 127;
        W2t[n * 136 + k] = (n < 40) ? (_Float16)W2[k * 40 + n] : (_Float16)0;
    }
    __syncthreads();

    int lane = t & 63, w = t >> 6;
    int c = lane & 15, q = lane >> 4;
    int m0 = w * 32;

    float4v acc[2][3];
#pragma unroll
    for (int r = 0; r < 2; ++r)
#pragma unroll
        for (int nt = 0; nt < 3; ++nt) acc[r][nt] = (float4v)(0.f);

#pragma unroll
    for (int kk = 0; kk < 4; ++kk) {
        int k0 = kk * 32 + q * 8;
        half8 a0 = *(const half8*)&Zs[(m0 + c) * 136 + k0];
        half8 a1 = *(const half8*)&Zs[(m0 + 16 + c) * 136 + k0];
#pragma unroll
        for (int nt = 0; nt < 3; ++nt) {
            half8 bv = *(const half8*)&W2t[(nt * 16 + c) * 136 + k0];
            acc[0][nt] = __builtin_amdgcn_mfma_f32_16x16x32_f16(a0, bv, acc[0][nt], 0, 0, 0);
            acc[1][nt] = __builtin_amdgcn_mfma_f32_16x16x32_f16(a1, bv, acc[1][nt], 0, 0, 0);
        }
    }
    __syncthreads();   // Zs/W2t dead; reuse smem as fp16 tile T[128][58]
    _Float16* T = (_Float16*)smem;
#pragma unroll
    for (int r = 0; r < 2; ++r)
#pragma unroll
        for (int reg = 0; reg < 4; ++reg) {
            int rl = m0 + r * 16 + q * 4 + reg;
#pragma unroll
            for (int nt = 0; nt < 3; ++nt)
                T[rl * 58 + nt * 16 + c] = (_Float16)acc[r][nt][reg];
        }
    __syncthreads();
    for (int p = t; p < 128 * 20; p += 256) {
        int row = p / 20;
        int c2 = p % 20;
        int grow = i0 + row;
        if (grow < N)
            *(__half2*)(h2 + (size_t)grow * 40 + c2 * 2) =
                *(const __half2*)&T[row * 58 + c2 * 2];
    }
}

// y[i,:] = dinv[i]*(sum_s h2[s,:]*dinv[s] + h2[i,:]*dinv[i]) + b2
__global__ void agg2_kernel(const __half* __restrict__ h2, const int* __restrict__ rowstart,
                            const int* __restrict__ adj, const float* __restrict__ dinv,
                            const float* __restrict__ b2, float* __restrict__ y, int N) {
    int wave = threadIdx.x >> 6;
    int lane = threadIdx.x & 63;
    int i = blockIdx.x * 4 + wave;
    if (i >= N) return;
    int e = (lane >= 40) ? 2 : ((lane >= 20) ? 1 : 0);
    int f = lane - 20 * e;
    int s0 = rowstart[i], s1 = rowstart[i + 1];
    float ax = 0.f, ay = 0.f;
    if (lane < 60) {
        int n = s0 + e;
        for (; n + 9 < s1; n += 12) {
            int s[4];
            float w[4];
            float2 r[4];
#pragma unroll
            for (int q = 0; q < 4; ++q) s[q] = adj[n + 3 * q];
#pragma unroll
            for (int q = 0; q < 4; ++q) w[q] = dinv[s[q]];
#pragma unroll
            for (int q = 0; q < 4; ++q)
                r[q] = __half22float2(((const __half2*)(h2 + (size_t)s[q] * 40))[f]);
#pragma unroll
            for (int q = 0; q < 4; ++q) {
                ax += r[q].x * w[q];
                ay += r[q].y * w[q];
            }
        }
        for (; n < s1; n += 3) {
            int sa = adj[n];
            float wa = dinv[sa];
            float2 ra = __half22float2(((const __half2*)(h2 + (size_t)sa * 40))[f]);
            ax += ra.x * wa;
            ay += ra.y * wa;
        }
    }
    float sx = ax + __shfl(ax, lane + 20, 64) + __shfl(ax, lane + 40, 64);
    float sy = ay + __shfl(ay, lane + 20, 64) + __shfl(ay, lane + 40, 64);
    if (lane < 20) {
        float di = dinv[i];
        float2 hi = __half22float2(((const __half2*)(h2 + (size_t)i * 40))[lane]);
        float2 bb = ((const float2*)b2)[lane];
        float2 res;
        res.x = sx * di + hi.x * di * di + bb.x;
        res.y = sy * di + hi.y * di * di + bb.y;
        ((float2*)(y + (size_t)i * 40))[lane] = res;
    }
}

extern "C" void kernel_launch(void* const* d_in, const int* in_sizes, int n_in,
                              void* d_out, int out_size, void* d_ws, size_t ws_size,
                              hipStream_t stream) {
    const float* x  = (const float*)d_in[0];
    const int*   ei = (const int*)d_in[1];
    const float* W1 = (const float*)d_in[2];
    const float* b1 = (const float*)d_in[3];
    const float* W2 = (const float*)d_in[4];
    const float* b2 = (const float*)d_in[5];
    float* y = (float*)d_out;

    const int H = in_sizes[3];           // 128
    const int F = in_sizes[2] / H;       // 128
    const int N = in_sizes[0] / F;       // 50000
    const int E = in_sizes[1] / 2;       // 800000
    (void)H; (void)ws_size; (void)n_in; (void)out_size;

    const int nbk = (N + 255) >> 8;              // 196 buckets (<=256)
    const int nchunks = (E + CHUNK - 1) / CHUNK; // 391 (<=512)
    const int nbt = (N + 127) / 128;             // 391 gemm tiles

    size_t off = 0;
    auto carve = [&](size_t bytes) -> void* {
        void* p = (char*)d_ws + off;
        off += (bytes + 255) & ~(size_t)255;
        return p;
    };
    int*           histT    = (int*)carve((size_t)nbk * nchunks * 4);
    int*           tot      = (int*)carve((size_t)nbk * 4);
    unsigned*      bkt      = (unsigned*)carve((size_t)E * 4);
    int*           rowstart = (int*)carve((size_t)(N + 1) * 4);
    float*         dinv     = (float*)carve((size_t)N * 4);
    int*           adj      = (int*)carve((size_t)E * 4);
    unsigned char* h1       = (unsigned char*)carve((size_t)N * 128);   // fp8 e4m3
    __half*        z        = (__half*)carve((size_t)N * FDIM * 2);
    _Float16*      Wt       = (_Float16*)carve((size_t)128 * 128 * 2);  // W1 fp16-T
    int*           bar      = (int*)carve(256);                         // grid barrier
    __half*        h2       = (__half*)h1;   // h1 dead after agg1; N x 40 fp16 fits

    // Persistent-kernel grid: min(jobs, co-resident capacity). Capacity from
    // the occupancy API so the grid_barrier's co-residency assumption holds.
    static int gridB = 0;
    if (gridB == 0) {
        int mb = 0;
        if (hipOccupancyMaxActiveBlocksPerMultiprocessor(&mb, build_kernel, 256, 0) != hipSuccess || mb < 1)
            mb = 2;   // conservative fallback (LDS 34816B allows >=4)
        int ncu = 0;
        if (hipDeviceGetAttribute(&ncu, hipDeviceAttributeMultiprocessorCount, 0) != hipSuccess || ncu < 1)
            ncu = 256;
        long cap  = (long)mb * ncu;
        long want = (long)nbk + nbt;   // 587: offsets || gemm all-parallel
        gridB = (int)(cap < want ? cap : want);
    }

    hipMemsetAsync(bar, 0, 16, stream);
    build_kernel<<<gridB, 256, 0, stream>>>(x, ei, W1, E, N, nchunks, nbk, nbt,
                                            histT, tot, bkt, adj, rowstart, dinv,
                                            Wt, h1, bar);
    agg1_kernel<<<(N + 3) / 4, 256, 0, stream>>>(h1, rowstart, adj, dinv, x, b1, z, N);
    gemm2_mfma<<<nbt, 256, 0, stream>>>(z, W2, h2, N);
    agg2_kernel<<<(N + 3) / 4, 256, 0, stream>>>(h2, rowstart, adj, dinv, b2, y, N);
}

// Round 3
// 321.682 us; speedup vs baseline: 1.4281x; 1.4281x over previous
//
#include <hip/hip_runtime.h>
#include <hip/hip_fp16.h>

// 2-layer GCN, pull-based CSR aggregation. fp32 math; h1 fp8-e4m3, z/h2 fp16.
// R18: R16's fused persistent kernel with the grid_barrier fix, now using
// __builtin_amdgcn_fence (R17's __hip_atomic_thread_fence doesn't exist).
// R16 post-mortem: polling with ACQUIRE/agent atomic loads emits a full L2
// buffer_inv per poll -> thousands of whole-L2 invalidates while straggler
// blocks still work -> 458us of stall (VALUBusy 0.7%, HBM 2%). Fix =
// cooperative-groups pattern: ONE release fence before the arrival add,
// RELAXED spin loads (no cache maintenance), ONE acquire fence after.
// (R15: LDS counting-sort scatter; R14: agg1 2-wave split regressed; R10:
// stride-132 fp32 epilogue; R5/R6: no global atomics in CSR build.)

#define FDIM 128
#define CHUNK 2048   // edges per chunk; nchunks = ceil(E/CHUNK) must be <= 512

using half8   = __attribute__((ext_vector_type(8))) _Float16;
using float4v = __attribute__((ext_vector_type(4))) float;
using float2v = __attribute__((ext_vector_type(2))) float;

__device__ __forceinline__ float2v fp8x2_to_f32x2(unsigned short hv) {
    return __builtin_amdgcn_cvt_pk_f32_fp8((int)hv, false);
}

// Device-scope grid barrier (co-resident grid, occupancy-sized). Cumulative
// single-cell count: target for barrier k is k*gridDim.x (monotonic, no reset
// races). RELAXED spin: agent-scope relaxed loads observe the remote RMW but
// emit NO per-poll cache maintenance. The single release fence writes back
// this XCD's L2 once; the single acquire fence invalidates stale lines once
// before we read other blocks' output.
__device__ __forceinline__ void grid_barrier(int* bar, int target) {
    __syncthreads();
    if (threadIdx.x == 0) {
        __builtin_amdgcn_fence(__ATOMIC_RELEASE, "agent");
        __hip_atomic_fetch_add(bar, 1, __ATOMIC_RELAXED, __HIP_MEMORY_SCOPE_AGENT);
        while (__hip_atomic_load(bar, __ATOMIC_RELAXED, __HIP_MEMORY_SCOPE_AGENT) < target)
            __builtin_amdgcn_s_sleep(4);
        __builtin_amdgcn_fence(__ATOMIC_ACQUIRE, "agent");
    }
    __syncthreads();
}

// Phases:
//  P0: per-chunk dst histogram (nchunks jobs) + W1 -> fp16-transposed (16 slices)
//  P1: per-bucket chunk-offset scan (nbk jobs)  ||  gemm1 MFMA tiles (nbt jobs)
//  P2: scatter with LDS counting sort (nchunks jobs)
//  P3: CSR finalize per bucket (nbk jobs)
__global__ void build_kernel(const float* __restrict__ x, const int* __restrict__ ei,
                             const float* __restrict__ W1,
                             int E, int N, int nchunks, int nbk, int nbt,
                             int* __restrict__ histT, int* __restrict__ tot,
                             unsigned* __restrict__ bkt, int* __restrict__ adj,
                             int* __restrict__ rowstart, float* __restrict__ dinv,
                             _Float16* __restrict__ Wt, unsigned char* __restrict__ h1,
                             int* __restrict__ bar) {
    __shared__ __align__(16) unsigned char smem[34816];
    const int nb = gridDim.x;
    const int t  = threadIdx.x;

    // ---------------- P0: histogram + W1 fp16 transpose --------------------
    for (int j = blockIdx.x; j < nchunks + 16; j += nb) {
        if (j < nchunks) {
            int* hist = (int*)smem;
            hist[t] = 0;
            __syncthreads();
            const int* dst = ei + E;
            int base = j * CHUNK;
#pragma unroll
            for (int k = 0; k < CHUNK / 256; ++k) {
                int e = base + k * 256 + t;
                if (e < E) atomicAdd(&hist[dst[e] >> 8], 1);
            }
            __syncthreads();
            if (t < nbk) histT[t * nchunks + j] = hist[t];
            __syncthreads();
        } else {
            // W1[k][n] (fp32) -> Wt[n][k] (fp16), 1024 elems per slice.
            int p = (j - nchunks) * 1024 + t;
#pragma unroll
            for (int k = 0; k < 4; ++k, p += 256) {
                int n = p >> 7, kk = p & 127;
                Wt[n * 128 + kk] = (_Float16)W1[kk * 128 + n];
            }
        }
    }
    grid_barrier(bar, 1 * nb);

    // ---------------- P1: offsets scan || gemm1 ----------------------------
    for (int j = blockIdx.x; j < nbk + nbt; j += nb) {
        if (j < nbk) {
            // exclusive scan of <=512 chunk counts; 2 slots/thread Hillis-Steele
            int* s = (int*)smem;
            __syncthreads();
            int* row = histT + (size_t)j * nchunks;
            int v0 = (t < nchunks) ? row[t] : 0;
            int v1 = (t + 256 < nchunks) ? row[t + 256] : 0;
            s[t] = v0;
            s[t + 256] = v1;
            __syncthreads();
            for (int off = 1; off < 512; off <<= 1) {
                int a  = (t >= off) ? s[t - off] : 0;
                int b2 = s[t + 256 - off];   // t+256 >= off always (off<=256)
                __syncthreads();
                s[t] += a;
                s[t + 256] += b2;
                __syncthreads();
            }
            if (t < nchunks) row[t] = s[t] - v0;                   // local excl offset
            if (t + 256 < nchunks) row[t + 256] = s[t + 256] - v1;
            if (t == 255) tot[j] = s[511];                         // bucket total
        } else {
            // ---- gemm1 tile: h1 = fp8(fp16(x) @ Wt^T), fp32 accum ----
            int tile = j - nbk;
            __syncthreads();   // guard smem reuse across jobs
            _Float16* Xs = (_Float16*)smem;   // 128 x 136 fp16 = 34816 B
            int i0 = tile * 128;
            for (int p = t; p < 128 * 32; p += 256) {
                int row = p >> 5;
                int col4 = (p & 31) * 4;
                int grow = i0 + row;
                float4 v = make_float4(0.f, 0.f, 0.f, 0.f);
                if (grow < N) v = *(const float4*)(x + (size_t)grow * FDIM + col4);
                _Float16* d = &Xs[row * 136 + col4];
                d[0] = (_Float16)v.x;
                d[1] = (_Float16)v.y;
                d[2] = (_Float16)v.z;
                d[3] = (_Float16)v.w;
            }
            __syncthreads();

            int lane = t & 63, w = t >> 6;
            int c = lane & 15, q = lane >> 4;
            int m0 = w * 32;

            float4v acc[2][8];
#pragma unroll
            for (int r = 0; r < 2; ++r)
#pragma unroll
                for (int nt = 0; nt < 8; ++nt) acc[r][nt] = (float4v)(0.f);

#pragma unroll
            for (int kk = 0; kk < 4; ++kk) {
                int k0 = kk * 32 + q * 8;
                half8 a0 = *(const half8*)&Xs[(m0 + c) * 136 + k0];
                half8 a1 = *(const half8*)&Xs[(m0 + 16 + c) * 136 + k0];
#pragma unroll
                for (int nt = 0; nt < 8; ++nt) {
                    half8 bv = *(const half8*)&Wt[(nt * 16 + c) * 128 + k0];  // L2-hit
                    acc[0][nt] = __builtin_amdgcn_mfma_f32_16x16x32_f16(a0, bv, acc[0][nt], 0, 0, 0);
                    acc[1][nt] = __builtin_amdgcn_mfma_f32_16x16x32_f16(a1, bv, acc[1][nt], 0, 0, 0);
                }
            }
            // epilogue in two 64-row half-tiles: T[64][132] fp32 = 33792 B fits
            float* T = (float*)smem;
#pragma unroll
            for (int half = 0; half < 2; ++half) {
                __syncthreads();
                if ((w >> 1) == half) {
#pragma unroll
                    for (int r = 0; r < 2; ++r)
#pragma unroll
                        for (int reg = 0; reg < 4; ++reg) {
                            int rl = (m0 & 63) + r * 16 + q * 4 + reg;
#pragma unroll
                            for (int nt = 0; nt < 8; ++nt)
                                T[rl * 132 + nt * 16 + c] = acc[r][nt][reg];
                        }
                }
                __syncthreads();
                for (int p = t; p < 64 * 32; p += 256) {
                    int row = p >> 5;
                    int col4 = (p & 31) * 4;
                    int grow = i0 + half * 64 + row;
                    if (grow < N) {
                        const float* src = &T[row * 132 + col4];
                        int lo = __builtin_amdgcn_cvt_pk_fp8_f32(src[0], src[1], 0, false);
                        int hi = __builtin_amdgcn_cvt_pk_fp8_f32(src[2], src[3], 0, false);
                        unsigned word = ((unsigned)lo & 0xFFFFu) | (((unsigned)hi & 0xFFFFu) << 16);
                        *(unsigned*)(h1 + (size_t)grow * 128 + col4) = word;
                    }
                }
            }
        }
    }
    grid_barrier(bar, 2 * nb);

    // ---------------- P2: scatter with in-LDS counting sort ----------------
    for (int j = blockIdx.x; j < nchunks; j += nb) {
        int* s        = (int*)smem;               // 256 ints
        int* delta    = (int*)(smem + 1024);      // 256 ints
        int* lcur     = (int*)(smem + 2048);      // 256 ints
        unsigned* buf = (unsigned*)(smem + 3072); // 2048 u32
        int* dst32    = (int*)(smem + 11264);     // 2048 ints
        __syncthreads();
        int v = (t < nbk) ? tot[t] : 0;
        s[t] = v;
        __syncthreads();
        for (int off = 1; off < 256; off <<= 1) {
            int tv = (t >= off) ? s[t - off] : 0;
            __syncthreads();
            s[t] += tv;
            __syncthreads();
        }
        int gbase = (t < nbk) ? (s[t] - v) + histT[t * nchunks + j] : 0;
        int lcnt = 0;
        if (t < nbk) {
            int cur_off = histT[t * nchunks + j];
            int nxt_off = (j + 1 < nchunks) ? histT[t * nchunks + j + 1] : tot[t];
            lcnt = nxt_off - cur_off;
        }
        __syncthreads();
        s[t] = lcnt;
        __syncthreads();
        for (int off = 1; off < 256; off <<= 1) {
            int tv = (t >= off) ? s[t - off] : 0;
            __syncthreads();
            s[t] += tv;
            __syncthreads();
        }
        int lofs = s[t] - lcnt;
        lcur[t] = lofs;
        delta[t] = gbase - lofs;
        __syncthreads();

        int base = j * CHUNK;
#pragma unroll
        for (int k = 0; k < CHUNK / 256; ++k) {
            int e = base + k * 256 + t;
            if (e < E) {
                int src = ei[e];
                int d = ei[E + e];
                int b = d >> 8;
                int pos = atomicAdd(&lcur[b], 1);   // LDS atomic
                buf[pos] = ((unsigned)(d & 255) << 24) | (unsigned)src;
                dst32[pos] = delta[b] + pos;
            }
        }
        __syncthreads();
        int cnt = min(CHUNK, E - base);
        for (int p = t; p < cnt; p += 256)
            bkt[dst32[p]] = buf[p];
    }
    grid_barrier(bar, 3 * nb);

    // ---------------- P3: CSR finalize per bucket --------------------------
    for (int j = blockIdx.x; j < nbk; j += nb) {
        int* sbuf = (int*)smem;
        int* hist = (int*)(smem + 1024);
        int* cur  = (int*)(smem + 2048);
        __syncthreads();
        int v = (t < nbk) ? tot[t] : 0;
        sbuf[t] = v;
        __syncthreads();
        for (int off = 1; off < 256; off <<= 1) {
            int tv = (t >= off) ? sbuf[t - off] : 0;
            __syncthreads();
            sbuf[t] += tv;
            __syncthreads();
        }
        int bb = sbuf[j] - tot[j];
        int nb_ = tot[j];
        __syncthreads();
        hist[t] = 0;
        __syncthreads();
        const unsigned* bk = bkt + bb;
        for (int e = t; e < nb_; e += 256) atomicAdd(&hist[bk[e] >> 24], 1);
        __syncthreads();
        int h_t = hist[t];
        sbuf[t] = h_t;
        __syncthreads();
        for (int off = 1; off < 256; off <<= 1) {
            int vv = (t >= off) ? sbuf[t - off] : 0;
            __syncthreads();
            sbuf[t] += vv;
            __syncthreads();
        }
        int excl_t = sbuf[t] - h_t;
        int node = j * 256 + t;
        if (node < N) {
            rowstart[node] = bb + excl_t;
            dinv[node] = rsqrtf((float)(h_t + 1));   // +1 self-loop
        }
        if (j == 0 && t == 0) rowstart[N] = E;
        cur[t] = excl_t;
        __syncthreads();
        for (int e = t; e < nb_; e += 256) {
            unsigned vv = bk[e];
            int pos = atomicAdd(&cur[vv >> 24], 1);   // LDS atomic
            adj[bb + pos] = (int)(vv & 0xFFFFFFu);    // src < 2^24
        }
    }
}

// z[i,:] = relu( dinv[i]*(sum_s h1[s,:]*dinv[s] + h1[i,:]*dinv[i]) + b1 ) + x[i,:]
// h1 fp8-e4m3, 128 B/row; lane = 2 feats; 8 gathers in flight. (R13 form.)
__global__ void agg1_kernel(const unsigned char* __restrict__ h1, const int* __restrict__ rowstart,
                            const int* __restrict__ adj, const float* __restrict__ dinv,
                            const float* __restrict__ x, const float* __restrict__ b1,
                            __half* __restrict__ z, int N) {
    int wave = threadIdx.x >> 6;
    int lane = threadIdx.x & 63;
    int i = blockIdx.x * 4 + wave;
    if (i >= N) return;
    int s0 = rowstart[i], s1 = rowstart[i + 1];
    float ax = 0.f, ay = 0.f;
    int n = s0;
    for (; n + 7 < s1; n += 8) {
        int s[8];
        float w[8];
        unsigned short hv[8];
#pragma unroll
        for (int q = 0; q < 8; ++q) s[q] = adj[n + q];
#pragma unroll
        for (int q = 0; q < 8; ++q) w[q] = dinv[s[q]];
#pragma unroll
        for (int q = 0; q < 8; ++q)
            hv[q] = *(const unsigned short*)(h1 + (size_t)s[q] * 128 + lane * 2);
#pragma unroll
        for (int q = 0; q < 8; ++q) {
            float2v f = fp8x2_to_f32x2(hv[q]);
            ax += f.x * w[q];
            ay += f.y * w[q];
        }
    }
    if (n + 3 < s1) {
        int s[4];
        float w[4];
        unsigned short hv[4];
#pragma unroll
        for (int q = 0; q < 4; ++q) s[q] = adj[n + q];
#pragma unroll
        for (int q = 0; q < 4; ++q) w[q] = dinv[s[q]];
#pragma unroll
        for (int q = 0; q < 4; ++q)
            hv[q] = *(const unsigned short*)(h1 + (size_t)s[q] * 128 + lane * 2);
#pragma unroll
        for (int q = 0; q < 4; ++q) {
            float2v f = fp8x2_to_f32x2(hv[q]);
            ax += f.x * w[q];
            ay += f.y * w[q];
        }
        n += 4;
    }
    for (; n < s1; ++n) {
        int sa = adj[n];
        float wa = dinv[sa];
        float2v f = fp8x2_to_f32x2(*(const unsigned short*)(h1 + (size_t)sa * 128 + lane * 2));
        ax += f.x * wa;
        ay += f.y * wa;
    }
    float di = dinv[i];
    float self = di * di;
    float2v hi = fp8x2_to_f32x2(*(const unsigned short*)(h1 + (size_t)i * 128 + lane * 2));
    ax = ax * di + hi.x * self;
    ay = ay * di + hi.y * self;
    float2 bb = ((const float2*)b1)[lane];
    float2 xi = ((const float2*)(x + (size_t)i * FDIM))[lane];
    float rx = fmaxf(ax + bb.x, 0.f) + xi.x;
    float ry = fmaxf(ay + bb.y, 0.f) + xi.y;
    ((__half2*)(z + (size_t)i * FDIM))[lane] = __floats2half2_rn(rx, ry);
}

// ---- MFMA GEMM2: h2 = z @ fp16(W2), fp32 accum, fp16 out (stride 40) ----
__launch_bounds__(256, 2)
__global__ void gemm2_mfma(const __half* __restrict__ z, const float* __restrict__ W2,
                           __half* __restrict__ h2, int N) {
    __shared__ __align__(16) unsigned char smem[49152];
    _Float16* Zs  = (_Float16*)smem;                 // 128*136*2 = 34816 B
    _Float16* W2t = (_Float16*)(smem + 34816);       // 48*136*2  = 13056 B
    int t = threadIdx.x;
    int i0 = blockIdx.x * 128;

    for (int p = t; p < 128 * 16; p += 256) {
        int row = p >> 4;
        int ck = (p & 15) * 8;
        int grow = i0 + row;
        half8 v = (half8)(_Float16)0;
        if (grow < N) v = *(const half8*)(z + (size_t)grow * FDIM + ck);
        *(half8*)&Zs[row * 136 + ck] = v;
    }
    for (int p = t; p < 48 * 128; p += 256) {
        int n = p >> 7;
        int k = p & 127;
        W2t[n * 136 + k] = (n < 40) ? (_Float16)W2[k * 40 + n] : (_Float16)0;
    }
    __syncthreads();

    int lane = t & 63, w = t >> 6;
    int c = lane & 15, q = lane >> 4;
    int m0 = w * 32;

    float4v acc[2][3];
#pragma unroll
    for (int r = 0; r < 2; ++r)
#pragma unroll
        for (int nt = 0; nt < 3; ++nt) acc[r][nt] = (float4v)(0.f);

#pragma unroll
    for (int kk = 0; kk < 4; ++kk) {
        int k0 = kk * 32 + q * 8;
        half8 a0 = *(const half8*)&Zs[(m0 + c) * 136 + k0];
        half8 a1 = *(const half8*)&Zs[(m0 + 16 + c) * 136 + k0];
#pragma unroll
        for (int nt = 0; nt < 3; ++nt) {
            half8 bv = *(const half8*)&W2t[(nt * 16 + c) * 136 + k0];
            acc[0][nt] = __builtin_amdgcn_mfma_f32_16x16x32_f16(a0, bv, acc[0][nt], 0, 0, 0);
            acc[1][nt] = __builtin_amdgcn_mfma_f32_16x16x32_f16(a1, bv, acc[1][nt], 0, 0, 0);
        }
    }
    __syncthreads();   // Zs/W2t dead; reuse smem as fp16 tile T[128][58]
    _Float16* T = (_Float16*)smem;
#pragma unroll
    for (int r = 0; r < 2; ++r)
#pragma unroll
        for (int reg = 0; reg < 4; ++reg) {
            int rl = m0 + r * 16 + q * 4 + reg;
#pragma unroll
            for (int nt = 0; nt < 3; ++nt)
                T[rl * 58 + nt * 16 + c] = (_Float16)acc[r][nt][reg];
        }
    __syncthreads();
    for (int p = t; p < 128 * 20; p += 256) {
        int row = p / 20;
        int c2 = p % 20;
        int grow = i0 + row;
        if (grow < N)
            *(__half2*)(h2 + (size_t)grow * 40 + c2 * 2) =
                *(const __half2*)&T[row * 58 + c2 * 2];
    }
}

// y[i,:] = dinv[i]*(sum_s h2[s,:]*dinv[s] + h2[i,:]*dinv[i]) + b2
__global__ void agg2_kernel(const __half* __restrict__ h2, const int* __restrict__ rowstart,
                            const int* __restrict__ adj, const float* __restrict__ dinv,
                            const float* __restrict__ b2, float* __restrict__ y, int N) {
    int wave = threadIdx.x >> 6;
    int lane = threadIdx.x & 63;
    int i = blockIdx.x * 4 + wave;
    if (i >= N) return;
    int e = (lane >= 40) ? 2 : ((lane >= 20) ? 1 : 0);
    int f = lane - 20 * e;
    int s0 = rowstart[i], s1 = rowstart[i + 1];
    float ax = 0.f, ay = 0.f;
    if (lane < 60) {
        int n = s0 + e;
        for (; n + 9 < s1; n += 12) {
            int s[4];
            float w[4];
            float2 r[4];
#pragma unroll
            for (int q = 0; q < 4; ++q) s[q] = adj[n + 3 * q];
#pragma unroll
            for (int q = 0; q < 4; ++q) w[q] = dinv[s[q]];
#pragma unroll
            for (int q = 0; q < 4; ++q)
                r[q] = __half22float2(((const __half2*)(h2 + (size_t)s[q] * 40))[f]);
#pragma unroll
            for (int q = 0; q < 4; ++q) {
                ax += r[q].x * w[q];
                ay += r[q].y * w[q];
            }
        }
        for (; n < s1; n += 3) {
            int sa = adj[n];
            float wa = dinv[sa];
            float2 ra = __half22float2(((const __half2*)(h2 + (size_t)sa * 40))[f]);
            ax += ra.x * wa;
            ay += ra.y * wa;
        }
    }
    float sx = ax + __shfl(ax, lane + 20, 64) + __shfl(ax, lane + 40, 64);
    float sy = ay + __shfl(ay, lane + 20, 64) + __shfl(ay, lane + 40, 64);
    if (lane < 20) {
        float di = dinv[i];
        float2 hi = __half22float2(((const __half2*)(h2 + (size_t)i * 40))[lane]);
        float2 bb = ((const float2*)b2)[lane];
        float2 res;
        res.x = sx * di + hi.x * di * di + bb.x;
        res.y = sy * di + hi.y * di * di + bb.y;
        ((float2*)(y + (size_t)i * 40))[lane] = res;
    }
}

extern "C" void kernel_launch(void* const* d_in, const int* in_sizes, int n_in,
                              void* d_out, int out_size, void* d_ws, size_t ws_size,
                              hipStream_t stream) {
    const float* x  = (const float*)d_in[0];
    const int*   ei = (const int*)d_in[1];
    const float* W1 = (const float*)d_in[2];
    const float* b1 = (const float*)d_in[3];
    const float* W2 = (const float*)d_in[4];
    const float* b2 = (const float*)d_in[5];
    float* y = (float*)d_out;

    const int H = in_sizes[3];           // 128
    const int F = in_sizes[2] / H;       // 128
    const int N = in_sizes[0] / F;       // 50000
    const int E = in_sizes[1] / 2;       // 800000
    (void)H; (void)ws_size; (void)n_in; (void)out_size;

    const int nbk = (N + 255) >> 8;              // 196 buckets (<=256)
    const int nchunks = (E + CHUNK - 1) / CHUNK; // 391 (<=512)
    const int nbt = (N + 127) / 128;             // 391 gemm tiles

    size_t off = 0;
    auto carve = [&](size_t bytes) -> void* {
        void* p = (char*)d_ws + off;
        off += (bytes + 255) & ~(size_t)255;
        return p;
    };
    int*           histT    = (int*)carve((size_t)nbk * nchunks * 4);
    int*           tot      = (int*)carve((size_t)nbk * 4);
    unsigned*      bkt      = (unsigned*)carve((size_t)E * 4);
    int*           rowstart = (int*)carve((size_t)(N + 1) * 4);
    float*         dinv     = (float*)carve((size_t)N * 4);
    int*           adj      = (int*)carve((size_t)E * 4);
    unsigned char* h1       = (unsigned char*)carve((size_t)N * 128);   // fp8 e4m3
    __half*        z        = (__half*)carve((size_t)N * FDIM * 2);
    _Float16*      Wt       = (_Float16*)carve((size_t)128 * 128 * 2);  // W1 fp16-T
    int*           bar      = (int*)carve(256);                         // grid barrier
    __half*        h2       = (__half*)h1;   // h1 dead after agg1; N x 40 fp16 fits

    // Persistent-kernel grid: min(jobs, co-resident capacity). Capacity from
    // the occupancy API so the grid_barrier's co-residency assumption holds.
    static int gridB = 0;
    if (gridB == 0) {
        int mb = 0;
        if (hipOccupancyMaxActiveBlocksPerMultiprocessor(&mb, build_kernel, 256, 0) != hipSuccess || mb < 1)
            mb = 2;   // conservative fallback (LDS 34816B allows >=4)
        int ncu = 0;
        if (hipDeviceGetAttribute(&ncu, hipDeviceAttributeMultiprocessorCount, 0) != hipSuccess || ncu < 1)
            ncu = 256;
        long cap  = (long)mb * ncu;
        long want = (long)nbk + nbt;   // 587: offsets || gemm all-parallel
        gridB = (int)(cap < want ? cap : want);
    }

    (void)hipMemsetAsync(bar, 0, 16, stream);
    build_kernel<<<gridB, 256, 0, stream>>>(x, ei, W1, E, N, nchunks, nbk, nbt,
                                            histT, tot, bkt, adj, rowstart, dinv,
                                            Wt, h1, bar);
    agg1_kernel<<<(N + 3) / 4, 256, 0, stream>>>(h1, rowstart, adj, dinv, x, b1, z, N);
    gemm2_mfma<<<nbt, 256, 0, stream>>>(z, W2, h2, N);
    agg2_kernel<<<(N + 3) / 4, 256, 0, stream>>>(h2, rowstart, adj, dinv, b2, y, N);
}

// Round 4
// 257.783 us; speedup vs baseline: 1.7821x; 1.2479x over previous
//
#include <hip/hip_runtime.h>
#include <hip/hip_fp16.h>

// 2-layer GCN, pull-based CSR aggregation. fp32 math; h1 fp8-e4m3, z/h2 fp16.
// R19: fenceless grid barrier. R18 post-mortem: per-block agent RELEASE fence
// lowers to buffer_wbl2 (full 4MB L2 walk); 512 blocks x 3 barriers = ~64
// redundant L2 writebacks per XCD per barrier, serializing -> ~57us/barrier
// (build stuck at 200us, VALUBusy 1.6%). Fix: ALL cross-phase data inside the
// fused kernel (histT/tot/bkt, scalar u32) moves via relaxed AGENT-scope
// atomics (bypass L1/L2, served at L3 = the cross-XCD coherence point), so no
// dirty cross-phase line ever sits in an L2 and the barrier needs NO fences:
// syncthreads (vmcnt drain = through-stores acked at L3) -> relaxed add ->
// relaxed spin -> syncthreads. W1-transpose back in-LDS per gemm block (R0
// body) to avoid a cross-phase vector-load path. Bulk h1/adj/rowstart/dinv
// are consumed by LATER KERNELS (implicit end-of-kernel release) -> normal.
// R18: relaxed-spin fix (459->200us). R16: fusion. R15: LDS counting-sort
// scatter. R10: stride-132 fp32 epilogue. R5/R6: no global atomics in build.

#define FDIM 128
#define CHUNK 2048   // edges per chunk; nchunks = ceil(E/CHUNK) must be <= 512

using half8   = __attribute__((ext_vector_type(8))) _Float16;
using float4v = __attribute__((ext_vector_type(4))) float;
using float2v = __attribute__((ext_vector_type(2))) float;

__device__ __forceinline__ float2v fp8x2_to_f32x2(unsigned short hv) {
    return __builtin_amdgcn_cvt_pk_f32_fp8((int)hv, false);
}

__device__ __forceinline__ void a_store(int* p, int v) {
    __hip_atomic_store(p, v, __ATOMIC_RELAXED, __HIP_MEMORY_SCOPE_AGENT);
}
__device__ __forceinline__ int a_load(const int* p) {
    return __hip_atomic_load(p, __ATOMIC_RELAXED, __HIP_MEMORY_SCOPE_AGENT);
}
__device__ __forceinline__ void a_storeu(unsigned* p, unsigned v) {
    __hip_atomic_store(p, v, __ATOMIC_RELAXED, __HIP_MEMORY_SCOPE_AGENT);
}
__device__ __forceinline__ unsigned a_loadu(const unsigned* p) {
    return __hip_atomic_load(p, __ATOMIC_RELAXED, __HIP_MEMORY_SCOPE_AGENT);
}

// Fenceless device-scope grid barrier (co-resident occupancy-sized grid).
// Safe because ALL cross-phase data moves via agent-scope atomics (at L3):
// __syncthreads drains vmcnt, so this block's through-stores are acked at L3
// before the arrival add; waiters' atomic loads read L3 directly. Cumulative
// target (k*gridDim.x) -> no reset races. No wbl2, no inv, no per-poll cost.
__device__ __forceinline__ void grid_barrier(int* bar, int target) {
    __syncthreads();
    if (threadIdx.x == 0) {
        __hip_atomic_fetch_add(bar, 1, __ATOMIC_RELAXED, __HIP_MEMORY_SCOPE_AGENT);
        while (__hip_atomic_load(bar, __ATOMIC_RELAXED, __HIP_MEMORY_SCOPE_AGENT) < target)
            __builtin_amdgcn_s_sleep(2);
    }
    __syncthreads();
}

// Phases:
//  P0: per-chunk dst histogram (nchunks jobs)
//  P1: per-bucket chunk-offset scan (nbk jobs)  ||  gemm1 MFMA tiles (nbt jobs)
//  P2: scatter with LDS counting sort (nchunks jobs)
//  P3: CSR finalize per bucket (nbk jobs)
__global__ void build_kernel(const float* __restrict__ x, const int* __restrict__ ei,
                             const float* __restrict__ W1,
                             int E, int N, int nchunks, int nbk, int nbt,
                             int* __restrict__ histT, int* __restrict__ tot,
                             unsigned* __restrict__ bkt, int* __restrict__ adj,
                             int* __restrict__ rowstart, float* __restrict__ dinv,
                             unsigned char* __restrict__ h1, int* __restrict__ bar) {
    __shared__ __align__(16) unsigned char smem[69632];
    const int nb = gridDim.x;
    const int t  = threadIdx.x;

    // ---------------- P0: per-chunk histogram ------------------------------
    for (int j = blockIdx.x; j < nchunks; j += nb) {
        int* hist = (int*)smem;
        __syncthreads();
        hist[t] = 0;
        __syncthreads();
        const int* dst = ei + E;
        int base = j * CHUNK;
#pragma unroll
        for (int k = 0; k < CHUNK / 256; ++k) {
            int e = base + k * 256 + t;
            if (e < E) atomicAdd(&hist[dst[e] >> 8], 1);
        }
        __syncthreads();
        if (t < nbk) a_store(&histT[t * nchunks + j], hist[t]);
    }
    grid_barrier(bar, 1 * nb);

    // ---------------- P1: offsets scan || gemm1 ----------------------------
    for (int j = blockIdx.x; j < nbk + nbt; j += nb) {
        if (j < nbk) {
            // exclusive scan of <=512 chunk counts; 2 slots/thread Hillis-Steele
            int* s = (int*)smem;
            __syncthreads();
            int* row = histT + (size_t)j * nchunks;
            int v0 = (t < nchunks) ? a_load(&row[t]) : 0;
            int v1 = (t + 256 < nchunks) ? a_load(&row[t + 256]) : 0;
            s[t] = v0;
            s[t + 256] = v1;
            __syncthreads();
            for (int off = 1; off < 512; off <<= 1) {
                int a  = (t >= off) ? s[t - off] : 0;
                int b2 = s[t + 256 - off];   // t+256 >= off always (off<=256)
                __syncthreads();
                s[t] += a;
                s[t + 256] += b2;
                __syncthreads();
            }
            if (t < nchunks) a_store(&row[t], s[t] - v0);           // local excl offset
            if (t + 256 < nchunks) a_store(&row[t + 256], s[t + 256] - v1);
            if (t == 255) a_store(&tot[j], s[511]);                 // bucket total
        } else {
            // ---- gemm1 tile (R0 body): h1 = fp8(fp16(x) @ fp16(W1)) ----
            int tile = j - nbk;
            __syncthreads();   // guard smem reuse across jobs
            _Float16* Xs = (_Float16*)smem;             // 128*136*2 = 34816 B
            _Float16* Wt = (_Float16*)(smem + 34816);   // 128*136*2 = 34816 B
            int i0 = tile * 128;
            for (int p = t; p < 128 * 32; p += 256) {
                int row = p >> 5;
                int col4 = (p & 31) * 4;
                int grow = i0 + row;
                float4 v = make_float4(0.f, 0.f, 0.f, 0.f);
                if (grow < N) v = *(const float4*)(x + (size_t)grow * FDIM + col4);
                _Float16* d = &Xs[row * 136 + col4];
                d[0] = (_Float16)v.x;
                d[1] = (_Float16)v.y;
                d[2] = (_Float16)v.z;
                d[3] = (_Float16)v.w;
            }
            for (int p = t; p < 128 * 128; p += 256) {
                int k = p >> 7;
                int n = p & 127;
                Wt[n * 136 + k] = (_Float16)W1[k * 128 + n];
            }
            __syncthreads();

            int lane = t & 63, w = t >> 6;
            int c = lane & 15, q = lane >> 4;
            int m0 = w * 32;

            float4v acc[2][8];
#pragma unroll
            for (int r = 0; r < 2; ++r)
#pragma unroll
                for (int nt = 0; nt < 8; ++nt) acc[r][nt] = (float4v)(0.f);

#pragma unroll
            for (int kk = 0; kk < 4; ++kk) {
                int k0 = kk * 32 + q * 8;
                half8 a0 = *(const half8*)&Xs[(m0 + c) * 136 + k0];
                half8 a1 = *(const half8*)&Xs[(m0 + 16 + c) * 136 + k0];
#pragma unroll
                for (int nt = 0; nt < 8; ++nt) {
                    half8 bv = *(const half8*)&Wt[(nt * 16 + c) * 136 + k0];
                    acc[0][nt] = __builtin_amdgcn_mfma_f32_16x16x32_f16(a0, bv, acc[0][nt], 0, 0, 0);
                    acc[1][nt] = __builtin_amdgcn_mfma_f32_16x16x32_f16(a1, bv, acc[1][nt], 0, 0, 0);
                }
            }
            __syncthreads();   // staging dead; reuse smem as fp32 tile T[128][132]
            float* T = (float*)smem;
#pragma unroll
            for (int r = 0; r < 2; ++r)
#pragma unroll
                for (int reg = 0; reg < 4; ++reg) {
                    int rl = m0 + r * 16 + q * 4 + reg;
#pragma unroll
                    for (int nt = 0; nt < 8; ++nt)
                        T[rl * 132 + nt * 16 + c] = acc[r][nt][reg];
                }
            __syncthreads();
            for (int p = t; p < 128 * 32; p += 256) {
                int row = p >> 5;
                int col4 = (p & 31) * 4;
                int grow = i0 + row;
                if (grow < N) {
                    const float* src = &T[row * 132 + col4];
                    int lo = __builtin_amdgcn_cvt_pk_fp8_f32(src[0], src[1], 0, false);
                    int hi = __builtin_amdgcn_cvt_pk_fp8_f32(src[2], src[3], 0, false);
                    unsigned word = ((unsigned)lo & 0xFFFFu) | (((unsigned)hi & 0xFFFFu) << 16);
                    *(unsigned*)(h1 + (size_t)grow * 128 + col4) = word;  // next-kernel consumer
                }
            }
        }
    }
    grid_barrier(bar, 2 * nb);

    // ---------------- P2: scatter with in-LDS counting sort ----------------
    for (int j = blockIdx.x; j < nchunks; j += nb) {
        int* s        = (int*)smem;               // 256 ints
        int* delta    = (int*)(smem + 1024);      // 256 ints
        int* lcur     = (int*)(smem + 2048);      // 256 ints
        unsigned* buf = (unsigned*)(smem + 3072); // 2048 u32
        int* dst32    = (int*)(smem + 11264);     // 2048 ints
        __syncthreads();
        int v = (t < nbk) ? a_load(&tot[t]) : 0;
        s[t] = v;
        __syncthreads();
        for (int off = 1; off < 256; off <<= 1) {
            int tv = (t >= off) ? s[t - off] : 0;
            __syncthreads();
            s[t] += tv;
            __syncthreads();
        }
        int gbase = 0, lcnt = 0;
        if (t < nbk) {
            int cur_off = a_load(&histT[t * nchunks + j]);
            gbase = (s[t] - v) + cur_off;
            int nxt_off = (j + 1 < nchunks) ? a_load(&histT[t * nchunks + j + 1]) : v;
            lcnt = nxt_off - cur_off;
        }
        __syncthreads();
        s[t] = lcnt;
        __syncthreads();
        for (int off = 1; off < 256; off <<= 1) {
            int tv = (t >= off) ? s[t - off] : 0;
            __syncthreads();
            s[t] += tv;
            __syncthreads();
        }
        int lofs = s[t] - lcnt;
        lcur[t] = lofs;
        delta[t] = gbase - lofs;
        __syncthreads();

        int base = j * CHUNK;
#pragma unroll
        for (int k = 0; k < CHUNK / 256; ++k) {
            int e = base + k * 256 + t;
            if (e < E) {
                int src = ei[e];
                int d = ei[E + e];
                int b = d >> 8;
                int pos = atomicAdd(&lcur[b], 1);   // LDS atomic
                buf[pos] = ((unsigned)(d & 255) << 24) | (unsigned)src;
                dst32[pos] = delta[b] + pos;
            }
        }
        __syncthreads();
        int cnt = min(CHUNK, E - base);
        for (int p = t; p < cnt; p += 256)
            a_storeu(&bkt[dst32[p]], buf[p]);
    }
    grid_barrier(bar, 3 * nb);

    // ---------------- P3: CSR finalize per bucket --------------------------
    for (int j = blockIdx.x; j < nbk; j += nb) {
        int* sbuf = (int*)smem;
        int* hist = (int*)(smem + 1024);
        int* cur  = (int*)(smem + 2048);
        __syncthreads();
        int v = (t < nbk) ? a_load(&tot[t]) : 0;
        sbuf[t] = v;
        __syncthreads();
        for (int off = 1; off < 256; off <<= 1) {
            int tv = (t >= off) ? sbuf[t - off] : 0;
            __syncthreads();
            sbuf[t] += tv;
            __syncthreads();
        }
        int bb = sbuf[j] - a_load(&tot[j]);
        int nb_ = a_load(&tot[j]);
        __syncthreads();
        hist[t] = 0;
        __syncthreads();
        const unsigned* bk = bkt + bb;
        for (int e = t; e < nb_; e += 256) atomicAdd(&hist[a_loadu(&bk[e]) >> 24], 1);
        __syncthreads();
        int h_t = hist[t];
        sbuf[t] = h_t;
        __syncthreads();
        for (int off = 1; off < 256; off <<= 1) {
            int vv = (t >= off) ? sbuf[t - off] : 0;
            __syncthreads();
            sbuf[t] += vv;
            __syncthreads();
        }
        int excl_t = sbuf[t] - h_t;
        int node = j * 256 + t;
        if (node < N) {
            rowstart[node] = bb + excl_t;              // next-kernel consumer
            dinv[node] = rsqrtf((float)(h_t + 1));     // +1 self-loop
        }
        if (j == 0 && t == 0) rowstart[N] = E;
        cur[t] = excl_t;
        __syncthreads();
        for (int e = t; e < nb_; e += 256) {
            unsigned vv = a_loadu(&bk[e]);
            int pos = atomicAdd(&cur[vv >> 24], 1);    // LDS atomic
            adj[bb + pos] = (int)(vv & 0xFFFFFFu);     // src < 2^24; next-kernel consumer
        }
    }
}

// z[i,:] = relu( dinv[i]*(sum_s h1[s,:]*dinv[s] + h1[i,:]*dinv[i]) + b1 ) + x[i,:]
// h1 fp8-e4m3, 128 B/row; lane = 2 feats; 8 gathers in flight. (R13 form.)
__global__ void agg1_kernel(const unsigned char* __restrict__ h1, const int* __restrict__ rowstart,
                            const int* __restrict__ adj, const float* __restrict__ dinv,
                            const float* __restrict__ x, const float* __restrict__ b1,
                            __half* __restrict__ z, int N) {
    int wave = threadIdx.x >> 6;
    int lane = threadIdx.x & 63;
    int i = blockIdx.x * 4 + wave;
    if (i >= N) return;
    int s0 = rowstart[i], s1 = rowstart[i + 1];
    float ax = 0.f, ay = 0.f;
    int n = s0;
    for (; n + 7 < s1; n += 8) {
        int s[8];
        float w[8];
        unsigned short hv[8];
#pragma unroll
        for (int q = 0; q < 8; ++q) s[q] = adj[n + q];
#pragma unroll
        for (int q = 0; q < 8; ++q) w[q] = dinv[s[q]];
#pragma unroll
        for (int q = 0; q < 8; ++q)
            hv[q] = *(const unsigned short*)(h1 + (size_t)s[q] * 128 + lane * 2);
#pragma unroll
        for (int q = 0; q < 8; ++q) {
            float2v f = fp8x2_to_f32x2(hv[q]);
            ax += f.x * w[q];
            ay += f.y * w[q];
        }
    }
    if (n + 3 < s1) {
        int s[4];
        float w[4];
        unsigned short hv[4];
#pragma unroll
        for (int q = 0; q < 4; ++q) s[q] = adj[n + q];
#pragma unroll
        for (int q = 0; q < 4; ++q) w[q] = dinv[s[q]];
#pragma unroll
        for (int q = 0; q < 4; ++q)
            hv[q] = *(const unsigned short*)(h1 + (size_t)s[q] * 128 + lane * 2);
#pragma unroll
        for (int q = 0; q < 4; ++q) {
            float2v f = fp8x2_to_f32x2(hv[q]);
            ax += f.x * w[q];
            ay += f.y * w[q];
        }
        n += 4;
    }
    for (; n < s1; ++n) {
        int sa = adj[n];
        float wa = dinv[sa];
        float2v f = fp8x2_to_f32x2(*(const unsigned short*)(h1 + (size_t)sa * 128 + lane * 2));
        ax += f.x * wa;
        ay += f.y * wa;
    }
    float di = dinv[i];
    float self = di * di;
    float2v hi = fp8x2_to_f32x2(*(const unsigned short*)(h1 + (size_t)i * 128 + lane * 2));
    ax = ax * di + hi.x * self;
    ay = ay * di + hi.y * self;
    float2 bb = ((const float2*)b1)[lane];
    float2 xi = ((const float2*)(x + (size_t)i * FDIM))[lane];
    float rx = fmaxf(ax + bb.x, 0.f) + xi.x;
    float ry = fmaxf(ay + bb.y, 0.f) + xi.y;
    ((__half2*)(z + (size_t)i * FDIM))[lane] = __floats2half2_rn(rx, ry);
}

// ---- MFMA GEMM2: h2 = z @ fp16(W2), fp32 accum, fp16 out (stride 40) ----
__launch_bounds__(256, 2)
__global__ void gemm2_mfma(const __half* __restrict__ z, const float* __restrict__ W2,
                           __half* __restrict__ h2, int N) {
    __shared__ __align__(16) unsigned char smem[49152];
    _Float16* Zs  = (_Float16*)smem;                 // 128*136*2 = 34816 B
    _Float16* W2t = (_Float16*)(smem + 34816);       // 48*136*2  = 13056 B
    int t = threadIdx.x;
    int i0 = blockIdx.x * 128;

    for (int p = t; p < 128 * 16; p += 256) {
        int row = p >> 4;
        int ck = (p & 15) * 8;
        int grow = i0 + row;
        half8 v = (half8)(_Float16)0;
        if (grow < N) v = *(const half8*)(z + (size_t)grow * FDIM + ck);
        *(half8*)&Zs[row * 136 + ck] = v;
    }
    for (int p = t; p < 48 * 128; p += 256) {
        int n = p >> 7;
        int k = p & 127;
        W2t[n * 136 + k] = (n < 40) ? (_Float16)W2[k * 40 + n] : (_Float16)0;
    }
    __syncthreads();

    int lane = t & 63, w = t >> 6;
    int c = lane & 15, q = lane >> 4;
    int m0 = w * 32;

    float4v acc[2][3];
#pragma unroll
    for (int r = 0; r < 2; ++r)
#pragma unroll
        for (int nt = 0; nt < 3; ++nt) acc[r][nt] = (float4v)(0.f);

#pragma unroll
    for (int kk = 0; kk < 4; ++kk) {
        int k0 = kk * 32 + q * 8;
        half8 a0 = *(const half8*)&Zs[(m0 + c) * 136 + k0];
        half8 a1 = *(const half8*)&Zs[(m0 + 16 + c) * 136 + k0];
#pragma unroll
        for (int nt = 0; nt < 3; ++nt) {
            half8 bv = *(const half8*)&W2t[(nt * 16 + c) * 136 + k0];
            acc[0][nt] = __builtin_amdgcn_mfma_f32_16x16x32_f16(a0, bv, acc[0][nt], 0, 0, 0);
            acc[1][nt] = __builtin_amdgcn_mfma_f32_16x16x32_f16(a1, bv, acc[1][nt], 0, 0, 0);
        }
    }
    __syncthreads();   // Zs/W2t dead; reuse smem as fp16 tile T[128][58]
    _Float16* T = (_Float16*)smem;
#pragma unroll
    for (int r = 0; r < 2; ++r)
#pragma unroll
        for (int reg = 0; reg < 4; ++reg) {
            int rl = m0 + r * 16 + q * 4 + reg;
#pragma unroll
            for (int nt = 0; nt < 3; ++nt)
                T[rl * 58 + nt * 16 + c] = (_Float16)acc[r][nt][reg];
        }
    __syncthreads();
    for (int p = t; p < 128 * 20; p += 256) {
        int row = p / 20;
        int c2 = p % 20;
        int grow = i0 + row;
        if (grow < N)
            *(__half2*)(h2 + (size_t)grow * 40 + c2 * 2) =
                *(const __half2*)&T[row * 58 + c2 * 2];
    }
}

// y[i,:] = dinv[i]*(sum_s h2[s,:]*dinv[s] + h2[i,:]*dinv[i]) + b2
__global__ void agg2_kernel(const __half* __restrict__ h2, const int* __restrict__ rowstart,
                            const int* __restrict__ adj, const float* __restrict__ dinv,
                            const float* __restrict__ b2, float* __restrict__ y, int N) {
    int wave = threadIdx.x >> 6;
    int lane = threadIdx.x & 63;
    int i = blockIdx.x * 4 + wave;
    if (i >= N) return;
    int e = (lane >= 40) ? 2 : ((lane >= 20) ? 1 : 0);
    int f = lane - 20 * e;
    int s0 = rowstart[i], s1 = rowstart[i + 1];
    float ax = 0.f, ay = 0.f;
    if (lane < 60) {
        int n = s0 + e;
        for (; n + 9 < s1; n += 12) {
            int s[4];
            float w[4];
            float2 r[4];
#pragma unroll
            for (int q = 0; q < 4; ++q) s[q] = adj[n + 3 * q];
#pragma unroll
            for (int q = 0; q < 4; ++q) w[q] = dinv[s[q]];
#pragma unroll
            for (int q = 0; q < 4; ++q)
                r[q] = __half22float2(((const __half2*)(h2 + (size_t)s[q] * 40))[f]);
#pragma unroll
            for (int q = 0; q < 4; ++q) {
                ax += r[q].x * w[q];
                ay += r[q].y * w[q];
            }
        }
        for (; n < s1; n += 3) {
            int sa = adj[n];
            float wa = dinv[sa];
            float2 ra = __half22float2(((const __half2*)(h2 + (size_t)sa * 40))[f]);
            ax += ra.x * wa;
            ay += ra.y * wa;
        }
    }
    float sx = ax + __shfl(ax, lane + 20, 64) + __shfl(ax, lane + 40, 64);
    float sy = ay + __shfl(ay, lane + 20, 64) + __shfl(ay, lane + 40, 64);
    if (lane < 20) {
        float di = dinv[i];
        float2 hi = __half22float2(((const __half2*)(h2 + (size_t)i * 40))[lane]);
        float2 bb = ((const float2*)b2)[lane];
        float2 res;
        res.x = sx * di + hi.x * di * di + bb.x;
        res.y = sy * di + hi.y * di * di + bb.y;
        ((float2*)(y + (size_t)i * 40))[lane] = res;
    }
}

extern "C" void kernel_launch(void* const* d_in, const int* in_sizes, int n_in,
                              void* d_out, int out_size, void* d_ws, size_t ws_size,
                              hipStream_t stream) {
    const float* x  = (const float*)d_in[0];
    const int*   ei = (const int*)d_in[1];
    const float* W1 = (const float*)d_in[2];
    const float* b1 = (const float*)d_in[3];
    const float* W2 = (const float*)d_in[4];
    const float* b2 = (const float*)d_in[5];
    float* y = (float*)d_out;

    const int H = in_sizes[3];           // 128
    const int F = in_sizes[2] / H;       // 128
    const int N = in_sizes[0] / F;       // 50000
    const int E = in_sizes[1] / 2;       // 800000
    (void)H; (void)ws_size; (void)n_in; (void)out_size;

    const int nbk = (N + 255) >> 8;              // 196 buckets (<=256)
    const int nchunks = (E + CHUNK - 1) / CHUNK; // 391 (<=512)
    const int nbt = (N + 127) / 128;             // 391 gemm tiles

    size_t off = 0;
    auto carve = [&](size_t bytes) -> void* {
        void* p = (char*)d_ws + off;
        off += (bytes + 255) & ~(size_t)255;
        return p;
    };
    int*           histT    = (int*)carve((size_t)nbk * nchunks * 4);
    int*           tot      = (int*)carve((size_t)nbk * 4);
    unsigned*      bkt      = (unsigned*)carve((size_t)E * 4);
    int*           rowstart = (int*)carve((size_t)(N + 1) * 4);
    float*         dinv     = (float*)carve((size_t)N * 4);
    int*           adj      = (int*)carve((size_t)E * 4);
    unsigned char* h1       = (unsigned char*)carve((size_t)N * 128);   // fp8 e4m3
    __half*        z        = (__half*)carve((size_t)N * FDIM * 2);
    int*           bar      = (int*)carve(256);                         // grid barrier
    __half*        h2       = (__half*)h1;   // h1 dead after agg1; N x 40 fp16 fits

    // Persistent-kernel grid: min(jobs, co-resident capacity). Capacity from
    // the occupancy API so the grid_barrier's co-residency assumption holds.
    static int gridB = 0;
    if (gridB == 0) {
        int mb = 0;
        if (hipOccupancyMaxActiveBlocksPerMultiprocessor(&mb, build_kernel, 256, 0) != hipSuccess || mb < 1)
            mb = 2;   // conservative fallback (LDS 69632B allows 2)
        int ncu = 0;
        if (hipDeviceGetAttribute(&ncu, hipDeviceAttributeMultiprocessorCount, 0) != hipSuccess || ncu < 1)
            ncu = 256;
        long cap  = (long)mb * ncu;
        long want = (long)nbk + nbt;   // 587: offsets || gemm all-parallel
        gridB = (int)(cap < want ? cap : want);
    }

    (void)hipMemsetAsync(bar, 0, 16, stream);
    build_kernel<<<gridB, 256, 0, stream>>>(x, ei, W1, E, N, nchunks, nbk, nbt,
                                            histT, tot, bkt, adj, rowstart, dinv,
                                            h1, bar);
    agg1_kernel<<<(N + 3) / 4, 256, 0, stream>>>(h1, rowstart, adj, dinv, x, b1, z, N);
    gemm2_mfma<<<nbt, 256, 0, stream>>>(z, W2, h2, N);
    agg2_kernel<<<(N + 3) / 4, 256, 0, stream>>>(h2, rowstart, adj, dinv, b2, y, N);
}

// Round 5
// 196.769 us; speedup vs baseline: 2.3347x; 1.3101x over previous
//
#include <hip/hip_runtime.h>
#include <hip/hip_fp16.h>

// 2-layer GCN, pull-based CSR aggregation. fp32 math; h1 fp8-e4m3, z/h2 fp16.
// R20: tree grid-barrier. R19 post-mortem: fenceless barrier fixed the L2
// wbl2/inv cost (200->120us) but ALL 512 blocks RMW one 4B cell and spin-load
// the same line -> arrival RMWs queue behind ~4 spin-loads/cy at one L3 bank,
// ~30us/barrier x3 = the 80us residual (VALUBusy 3.2%, HBM 4%). Fix: 32
// arrival cells on distinct 64B lines (<=16 serialized RMWs each, parallel
// across banks) -> per-cell last arriver RMWs root -> final arriver stores
// phase to a SEPARATE release line; spinners read-only that line. Cumulative
// targets, no resets. Cross-phase data still via relaxed agent atomics (R19).
// R18: relaxed spin (459->200). R16: fusion. R15: LDS counting-sort scatter.
// R10: stride-132 fp32 epilogue. R5/R6: no global atomics in build.

#define FDIM 128
#define CHUNK 2048   // edges per chunk; nchunks = ceil(E/CHUNK) must be <= 512
#define NCELL 32     // barrier arrival cells (64B apart)

using half8   = __attribute__((ext_vector_type(8))) _Float16;
using float4v = __attribute__((ext_vector_type(4))) float;
using float2v = __attribute__((ext_vector_type(2))) float;

__device__ __forceinline__ float2v fp8x2_to_f32x2(unsigned short hv) {
    return __builtin_amdgcn_cvt_pk_f32_fp8((int)hv, false);
}

__device__ __forceinline__ void a_store(int* p, int v) {
    __hip_atomic_store(p, v, __ATOMIC_RELAXED, __HIP_MEMORY_SCOPE_AGENT);
}
__device__ __forceinline__ int a_load(const int* p) {
    return __hip_atomic_load(p, __ATOMIC_RELAXED, __HIP_MEMORY_SCOPE_AGENT);
}
__device__ __forceinline__ void a_storeu(unsigned* p, unsigned v) {
    __hip_atomic_store(p, v, __ATOMIC_RELAXED, __HIP_MEMORY_SCOPE_AGENT);
}
__device__ __forceinline__ unsigned a_loadu(const unsigned* p) {
    return __hip_atomic_load(p, __ATOMIC_RELAXED, __HIP_MEMORY_SCOPE_AGENT);
}

// Tree grid-barrier (co-resident occupancy-sized grid), fenceless (all
// cross-phase data moves via agent-scope atomics at the L3 coherence point;
// __syncthreads drains vmcnt so stores are acked before arrival).
// Layout in barArea (ints): cells at [cell*16] (64B apart), root at [NCELL*16],
// release at [NCELL*16+16]. Cumulative targets: cell c fills to phase*ccnt,
// root to phase*ncells_used, release publishes `phase`. No resets -> no races.
// Causality: rel=phase is stored only after every cell reached its target,
// i.e. after every block's arrival RMW, i.e. after all data stores hit L3.
__device__ __forceinline__ void grid_barrier(int* barArea, int nb, int phase) {
    __syncthreads();
    if (threadIdx.x == 0) {
        const int cell  = blockIdx.x & (NCELL - 1);
        int* cellp = barArea + cell * 16;
        int* rootp = barArea + NCELL * 16;
        int* relp  = barArea + NCELL * 16 + 16;
        const int ccnt  = (nb >> 5) + ((cell < (nb & (NCELL - 1))) ? 1 : 0);
        const int nused = (nb < NCELL) ? nb : NCELL;
        int old = __hip_atomic_fetch_add(cellp, 1, __ATOMIC_RELAXED, __HIP_MEMORY_SCOPE_AGENT);
        if (old == phase * ccnt - 1) {
            int rold = __hip_atomic_fetch_add(rootp, 1, __ATOMIC_RELAXED, __HIP_MEMORY_SCOPE_AGENT);
            if (rold == phase * nused - 1)
                a_store(relp, phase);
        }
        while (a_load(relp) < phase)
            __builtin_amdgcn_s_sleep(4);
    }
    __syncthreads();
}

// Phases:
//  P0: per-chunk dst histogram (nchunks jobs)
//  P1: per-bucket chunk-offset scan (nbk jobs)  ||  gemm1 MFMA tiles (nbt jobs)
//  P2: scatter with LDS counting sort (nchunks jobs)
//  P3: CSR finalize per bucket (nbk jobs)
__global__ void build_kernel(const float* __restrict__ x, const int* __restrict__ ei,
                             const float* __restrict__ W1,
                             int E, int N, int nchunks, int nbk, int nbt,
                             int* __restrict__ histT, int* __restrict__ tot,
                             unsigned* __restrict__ bkt, int* __restrict__ adj,
                             int* __restrict__ rowstart, float* __restrict__ dinv,
                             unsigned char* __restrict__ h1, int* __restrict__ bar) {
    __shared__ __align__(16) unsigned char smem[69632];
    const int nb = gridDim.x;
    const int t  = threadIdx.x;

    // ---------------- P0: per-chunk histogram ------------------------------
    for (int j = blockIdx.x; j < nchunks; j += nb) {
        int* hist = (int*)smem;
        __syncthreads();
        hist[t] = 0;
        __syncthreads();
        const int* dst = ei + E;
        int base = j * CHUNK;
#pragma unroll
        for (int k = 0; k < CHUNK / 256; ++k) {
            int e = base + k * 256 + t;
            if (e < E) atomicAdd(&hist[dst[e] >> 8], 1);
        }
        __syncthreads();
        if (t < nbk) a_store(&histT[t * nchunks + j], hist[t]);
    }
    grid_barrier(bar, nb, 1);

    // ---------------- P1: offsets scan || gemm1 ----------------------------
    for (int j = blockIdx.x; j < nbk + nbt; j += nb) {
        if (j < nbk) {
            // exclusive scan of <=512 chunk counts; 2 slots/thread Hillis-Steele
            int* s = (int*)smem;
            __syncthreads();
            int* row = histT + (size_t)j * nchunks;
            int v0 = (t < nchunks) ? a_load(&row[t]) : 0;
            int v1 = (t + 256 < nchunks) ? a_load(&row[t + 256]) : 0;
            s[t] = v0;
            s[t + 256] = v1;
            __syncthreads();
            for (int off = 1; off < 512; off <<= 1) {
                int a  = (t >= off) ? s[t - off] : 0;
                int b2 = s[t + 256 - off];   // t+256 >= off always (off<=256)
                __syncthreads();
                s[t] += a;
                s[t + 256] += b2;
                __syncthreads();
            }
            if (t < nchunks) a_store(&row[t], s[t] - v0);           // local excl offset
            if (t + 256 < nchunks) a_store(&row[t + 256], s[t + 256] - v1);
            if (t == 255) a_store(&tot[j], s[511]);                 // bucket total
        } else {
            // ---- gemm1 tile (R0 body): h1 = fp8(fp16(x) @ fp16(W1)) ----
            int tile = j - nbk;
            __syncthreads();   // guard smem reuse across jobs
            _Float16* Xs = (_Float16*)smem;             // 128*136*2 = 34816 B
            _Float16* Wt = (_Float16*)(smem + 34816);   // 128*136*2 = 34816 B
            int i0 = tile * 128;
            for (int p = t; p < 128 * 32; p += 256) {
                int row = p >> 5;
                int col4 = (p & 31) * 4;
                int grow = i0 + row;
                float4 v = make_float4(0.f, 0.f, 0.f, 0.f);
                if (grow < N) v = *(const float4*)(x + (size_t)grow * FDIM + col4);
                _Float16* d = &Xs[row * 136 + col4];
                d[0] = (_Float16)v.x;
                d[1] = (_Float16)v.y;
                d[2] = (_Float16)v.z;
                d[3] = (_Float16)v.w;
            }
            for (int p = t; p < 128 * 128; p += 256) {
                int k = p >> 7;
                int n = p & 127;
                Wt[n * 136 + k] = (_Float16)W1[k * 128 + n];
            }
            __syncthreads();

            int lane = t & 63, w = t >> 6;
            int c = lane & 15, q = lane >> 4;
            int m0 = w * 32;

            float4v acc[2][8];
#pragma unroll
            for (int r = 0; r < 2; ++r)
#pragma unroll
                for (int nt = 0; nt < 8; ++nt) acc[r][nt] = (float4v)(0.f);

#pragma unroll
            for (int kk = 0; kk < 4; ++kk) {
                int k0 = kk * 32 + q * 8;
                half8 a0 = *(const half8*)&Xs[(m0 + c) * 136 + k0];
                half8 a1 = *(const half8*)&Xs[(m0 + 16 + c) * 136 + k0];
#pragma unroll
                for (int nt = 0; nt < 8; ++nt) {
                    half8 bv = *(const half8*)&Wt[(nt * 16 + c) * 136 + k0];
                    acc[0][nt] = __builtin_amdgcn_mfma_f32_16x16x32_f16(a0, bv, acc[0][nt], 0, 0, 0);
                    acc[1][nt] = __builtin_amdgcn_mfma_f32_16x16x32_f16(a1, bv, acc[1][nt], 0, 0, 0);
                }
            }
            __syncthreads();   // staging dead; reuse smem as fp32 tile T[128][132]
            float* T = (float*)smem;
#pragma unroll
            for (int r = 0; r < 2; ++r)
#pragma unroll
                for (int reg = 0; reg < 4; ++reg) {
                    int rl = m0 + r * 16 + q * 4 + reg;
#pragma unroll
                    for (int nt = 0; nt < 8; ++nt)
                        T[rl * 132 + nt * 16 + c] = acc[r][nt][reg];
                }
            __syncthreads();
            for (int p = t; p < 128 * 32; p += 256) {
                int row = p >> 5;
                int col4 = (p & 31) * 4;
                int grow = i0 + row;
                if (grow < N) {
                    const float* src = &T[row * 132 + col4];
                    int lo = __builtin_amdgcn_cvt_pk_fp8_f32(src[0], src[1], 0, false);
                    int hi = __builtin_amdgcn_cvt_pk_fp8_f32(src[2], src[3], 0, false);
                    unsigned word = ((unsigned)lo & 0xFFFFu) | (((unsigned)hi & 0xFFFFu) << 16);
                    *(unsigned*)(h1 + (size_t)grow * 128 + col4) = word;  // next-kernel consumer
                }
            }
        }
    }
    grid_barrier(bar, nb, 2);

    // ---------------- P2: scatter with in-LDS counting sort ----------------
    for (int j = blockIdx.x; j < nchunks; j += nb) {
        int* s        = (int*)smem;               // 256 ints
        int* delta    = (int*)(smem + 1024);      // 256 ints
        int* lcur     = (int*)(smem + 2048);      // 256 ints
        unsigned* buf = (unsigned*)(smem + 3072); // 2048 u32
        int* dst32    = (int*)(smem + 11264);     // 2048 ints
        __syncthreads();
        int v = (t < nbk) ? a_load(&tot[t]) : 0;
        s[t] = v;
        __syncthreads();
        for (int off = 1; off < 256; off <<= 1) {
            int tv = (t >= off) ? s[t - off] : 0;
            __syncthreads();
            s[t] += tv;
            __syncthreads();
        }
        int gbase = 0, lcnt = 0;
        if (t < nbk) {
            int cur_off = a_load(&histT[t * nchunks + j]);
            gbase = (s[t] - v) + cur_off;
            int nxt_off = (j + 1 < nchunks) ? a_load(&histT[t * nchunks + j + 1]) : v;
            lcnt = nxt_off - cur_off;
        }
        __syncthreads();
        s[t] = lcnt;
        __syncthreads();
        for (int off = 1; off < 256; off <<= 1) {
            int tv = (t >= off) ? s[t - off] : 0;
            __syncthreads();
            s[t] += tv;
            __syncthreads();
        }
        int lofs = s[t] - lcnt;
        lcur[t] = lofs;
        delta[t] = gbase - lofs;
        __syncthreads();

        int base = j * CHUNK;
#pragma unroll
        for (int k = 0; k < CHUNK / 256; ++k) {
            int e = base + k * 256 + t;
            if (e < E) {
                int src = ei[e];
                int d = ei[E + e];
                int b = d >> 8;
                int pos = atomicAdd(&lcur[b], 1);   // LDS atomic
                buf[pos] = ((unsigned)(d & 255) << 24) | (unsigned)src;
                dst32[pos] = delta[b] + pos;
            }
        }
        __syncthreads();
        int cnt = min(CHUNK, E - base);
        for (int p = t; p < cnt; p += 256)
            a_storeu(&bkt[dst32[p]], buf[p]);
    }
    grid_barrier(bar, nb, 3);

    // ---------------- P3: CSR finalize per bucket --------------------------
    for (int j = blockIdx.x; j < nbk; j += nb) {
        int* sbuf = (int*)smem;
        int* hist = (int*)(smem + 1024);
        int* cur  = (int*)(smem + 2048);
        __syncthreads();
        int v = (t < nbk) ? a_load(&tot[t]) : 0;
        sbuf[t] = v;
        __syncthreads();
        for (int off = 1; off < 256; off <<= 1) {
            int tv = (t >= off) ? sbuf[t - off] : 0;
            __syncthreads();
            sbuf[t] += tv;
            __syncthreads();
        }
        int bb = sbuf[j] - a_load(&tot[j]);
        int nb_ = a_load(&tot[j]);
        __syncthreads();
        hist[t] = 0;
        __syncthreads();
        const unsigned* bk = bkt + bb;
        for (int e = t; e < nb_; e += 256) atomicAdd(&hist[a_loadu(&bk[e]) >> 24], 1);
        __syncthreads();
        int h_t = hist[t];
        sbuf[t] = h_t;
        __syncthreads();
        for (int off = 1; off < 256; off <<= 1) {
            int vv = (t >= off) ? sbuf[t - off] : 0;
            __syncthreads();
            sbuf[t] += vv;
            __syncthreads();
        }
        int excl_t = sbuf[t] - h_t;
        int node = j * 256 + t;
        if (node < N) {
            rowstart[node] = bb + excl_t;              // next-kernel consumer
            dinv[node] = rsqrtf((float)(h_t + 1));     // +1 self-loop
        }
        if (j == 0 && t == 0) rowstart[N] = E;
        cur[t] = excl_t;
        __syncthreads();
        for (int e = t; e < nb_; e += 256) {
            unsigned vv = a_loadu(&bk[e]);
            int pos = atomicAdd(&cur[vv >> 24], 1);    // LDS atomic
            adj[bb + pos] = (int)(vv & 0xFFFFFFu);     // src < 2^24; next-kernel consumer
        }
    }
}

// z[i,:] = relu( dinv[i]*(sum_s h1[s,:]*dinv[s] + h1[i,:]*dinv[i]) + b1 ) + x[i,:]
// h1 fp8-e4m3, 128 B/row; lane = 2 feats; 8 gathers in flight. (R13 form.)
__global__ void agg1_kernel(const unsigned char* __restrict__ h1, const int* __restrict__ rowstart,
                            const int* __restrict__ adj, const float* __restrict__ dinv,
                            const float* __restrict__ x, const float* __restrict__ b1,
                            __half* __restrict__ z, int N) {
    int wave = threadIdx.x >> 6;
    int lane = threadIdx.x & 63;
    int i = blockIdx.x * 4 + wave;
    if (i >= N) return;
    int s0 = rowstart[i], s1 = rowstart[i + 1];
    float ax = 0.f, ay = 0.f;
    int n = s0;
    for (; n + 7 < s1; n += 8) {
        int s[8];
        float w[8];
        unsigned short hv[8];
#pragma unroll
        for (int q = 0; q < 8; ++q) s[q] = adj[n + q];
#pragma unroll
        for (int q = 0; q < 8; ++q) w[q] = dinv[s[q]];
#pragma unroll
        for (int q = 0; q < 8; ++q)
            hv[q] = *(const unsigned short*)(h1 + (size_t)s[q] * 128 + lane * 2);
#pragma unroll
        for (int q = 0; q < 8; ++q) {
            float2v f = fp8x2_to_f32x2(hv[q]);
            ax += f.x * w[q];
            ay += f.y * w[q];
        }
    }
    if (n + 3 < s1) {
        int s[4];
        float w[4];
        unsigned short hv[4];
#pragma unroll
        for (int q = 0; q < 4; ++q) s[q] = adj[n + q];
#pragma unroll
        for (int q = 0; q < 4; ++q) w[q] = dinv[s[q]];
#pragma unroll
        for (int q = 0; q < 4; ++q)
            hv[q] = *(const unsigned short*)(h1 + (size_t)s[q] * 128 + lane * 2);
#pragma unroll
        for (int q = 0; q < 4; ++q) {
            float2v f = fp8x2_to_f32x2(hv[q]);
            ax += f.x * w[q];
            ay += f.y * w[q];
        }
        n += 4;
    }
    for (; n < s1; ++n) {
        int sa = adj[n];
        float wa = dinv[sa];
        float2v f = fp8x2_to_f32x2(*(const unsigned short*)(h1 + (size_t)sa * 128 + lane * 2));
        ax += f.x * wa;
        ay += f.y * wa;
    }
    float di = dinv[i];
    float self = di * di;
    float2v hi = fp8x2_to_f32x2(*(const unsigned short*)(h1 + (size_t)i * 128 + lane * 2));
    ax = ax * di + hi.x * self;
    ay = ay * di + hi.y * self;
    float2 bb = ((const float2*)b1)[lane];
    float2 xi = ((const float2*)(x + (size_t)i * FDIM))[lane];
    float rx = fmaxf(ax + bb.x, 0.f) + xi.x;
    float ry = fmaxf(ay + bb.y, 0.f) + xi.y;
    ((__half2*)(z + (size_t)i * FDIM))[lane] = __floats2half2_rn(rx, ry);
}

// ---- MFMA GEMM2: h2 = z @ fp16(W2), fp32 accum, fp16 out (stride 40) ----
__launch_bounds__(256, 2)
__global__ void gemm2_mfma(const __half* __restrict__ z, const float* __restrict__ W2,
                           __half* __restrict__ h2, int N) {
    __shared__ __align__(16) unsigned char smem[49152];
    _Float16* Zs  = (_Float16*)smem;                 // 128*136*2 = 34816 B
    _Float16* W2t = (_Float16*)(smem + 34816);       // 48*136*2  = 13056 B
    int t = threadIdx.x;
    int i0 = blockIdx.x * 128;

    for (int p = t; p < 128 * 16; p += 256) {
        int row = p >> 4;
        int ck = (p & 15) * 8;
        int grow = i0 + row;
        half8 v = (half8)(_Float16)0;
        if (grow < N) v = *(const half8*)(z + (size_t)grow * FDIM + ck);
        *(half8*)&Zs[row * 136 + ck] = v;
    }
    for (int p = t; p < 48 * 128; p += 256) {
        int n = p >> 7;
        int k = p & 127;
        W2t[n * 136 + k] = (n < 40) ? (_Float16)W2[k * 40 + n] : (_Float16)0;
    }
    __syncthreads();

    int lane = t & 63, w = t >> 6;
    int c = lane & 15, q = lane >> 4;
    int m0 = w * 32;

    float4v acc[2][3];
#pragma unroll
    for (int r = 0; r < 2; ++r)
#pragma unroll
        for (int nt = 0; nt < 3; ++nt) acc[r][nt] = (float4v)(0.f);

#pragma unroll
    for (int kk = 0; kk < 4; ++kk) {
        int k0 = kk * 32 + q * 8;
        half8 a0 = *(const half8*)&Zs[(m0 + c) * 136 + k0];
        half8 a1 = *(const half8*)&Zs[(m0 + 16 + c) * 136 + k0];
#pragma unroll
        for (int nt = 0; nt < 3; ++nt) {
            half8 bv = *(const half8*)&W2t[(nt * 16 + c) * 136 + k0];
            acc[0][nt] = __builtin_amdgcn_mfma_f32_16x16x32_f16(a0, bv, acc[0][nt], 0, 0, 0);
            acc[1][nt] = __builtin_amdgcn_mfma_f32_16x16x32_f16(a1, bv, acc[1][nt], 0, 0, 0);
        }
    }
    __syncthreads();   // Zs/W2t dead; reuse smem as fp16 tile T[128][58]
    _Float16* T = (_Float16*)smem;
#pragma unroll
    for (int r = 0; r < 2; ++r)
#pragma unroll
        for (int reg = 0; reg < 4; ++reg) {
            int rl = m0 + r * 16 + q * 4 + reg;
#pragma unroll
            for (int nt = 0; nt < 3; ++nt)
                T[rl * 58 + nt * 16 + c] = (_Float16)acc[r][nt][reg];
        }
    __syncthreads();
    for (int p = t; p < 128 * 20; p += 256) {
        int row = p / 20;
        int c2 = p % 20;
        int grow = i0 + row;
        if (grow < N)
            *(__half2*)(h2 + (size_t)grow * 40 + c2 * 2) =
                *(const __half2*)&T[row * 58 + c2 * 2];
    }
}

// y[i,:] = dinv[i]*(sum_s h2[s,:]*dinv[s] + h2[i,:]*dinv[i]) + b2
__global__ void agg2_kernel(const __half* __restrict__ h2, const int* __restrict__ rowstart,
                            const int* __restrict__ adj, const float* __restrict__ dinv,
                            const float* __restrict__ b2, float* __restrict__ y, int N) {
    int wave = threadIdx.x >> 6;
    int lane = threadIdx.x & 63;
    int i = blockIdx.x * 4 + wave;
    if (i >= N) return;
    int e = (lane >= 40) ? 2 : ((lane >= 20) ? 1 : 0);
    int f = lane - 20 * e;
    int s0 = rowstart[i], s1 = rowstart[i + 1];
    float ax = 0.f, ay = 0.f;
    if (lane < 60) {
        int n = s0 + e;
        for (; n + 9 < s1; n += 12) {
            int s[4];
            float w[4];
            float2 r[4];
#pragma unroll
            for (int q = 0; q < 4; ++q) s[q] = adj[n + 3 * q];
#pragma unroll
            for (int q = 0; q < 4; ++q) w[q] = dinv[s[q]];
#pragma unroll
            for (int q = 0; q < 4; ++q)
                r[q] = __half22float2(((const __half2*)(h2 + (size_t)s[q] * 40))[f]);
#pragma unroll
            for (int q = 0; q < 4; ++q) {
                ax += r[q].x * w[q];
                ay += r[q].y * w[q];
            }
        }
        for (; n < s1; n += 3) {
            int sa = adj[n];
            float wa = dinv[sa];
            float2 ra = __half22float2(((const __half2*)(h2 + (size_t)sa * 40))[f]);
            ax += ra.x * wa;
            ay += ra.y * wa;
        }
    }
    float sx = ax + __shfl(ax, lane + 20, 64) + __shfl(ax, lane + 40, 64);
    float sy = ay + __shfl(ay, lane + 20, 64) + __shfl(ay, lane + 40, 64);
    if (lane < 20) {
        float di = dinv[i];
        float2 hi = __half22float2(((const __half2*)(h2 + (size_t)i * 40))[lane]);
        float2 bb = ((const float2*)b2)[lane];
        float2 res;
        res.x = sx * di + hi.x * di * di + bb.x;
        res.y = sy * di + hi.y * di * di + bb.y;
        ((float2*)(y + (size_t)i * 40))[lane] = res;
    }
}

extern "C" void kernel_launch(void* const* d_in, const int* in_sizes, int n_in,
                              void* d_out, int out_size, void* d_ws, size_t ws_size,
                              hipStream_t stream) {
    const float* x  = (const float*)d_in[0];
    const int*   ei = (const int*)d_in[1];
    const float* W1 = (const float*)d_in[2];
    const float* b1 = (const float*)d_in[3];
    const float* W2 = (const float*)d_in[4];
    const float* b2 = (const float*)d_in[5];
    float* y = (float*)d_out;

    const int H = in_sizes[3];           // 128
    const int F = in_sizes[2] / H;       // 128
    const int N = in_sizes[0] / F;       // 50000
    const int E = in_sizes[1] / 2;       // 800000
    (void)H; (void)ws_size; (void)n_in; (void)out_size;

    const int nbk = (N + 255) >> 8;              // 196 buckets (<=256)
    const int nchunks = (E + CHUNK - 1) / CHUNK; // 391 (<=512)
    const int nbt = (N + 127) / 128;             // 391 gemm tiles

    size_t off = 0;
    auto carve = [&](size_t bytes) -> void* {
        void* p = (char*)d_ws + off;
        off += (bytes + 255) & ~(size_t)255;
        return p;
    };
    int*           histT    = (int*)carve((size_t)nbk * nchunks * 4);
    int*           tot      = (int*)carve((size_t)nbk * 4);
    unsigned*      bkt      = (unsigned*)carve((size_t)E * 4);
    int*           rowstart = (int*)carve((size_t)(N + 1) * 4);
    float*         dinv     = (float*)carve((size_t)N * 4);
    int*           adj      = (int*)carve((size_t)E * 4);
    unsigned char* h1       = (unsigned char*)carve((size_t)N * 128);   // fp8 e4m3
    __half*        z        = (__half*)carve((size_t)N * FDIM * 2);
    int*           bar      = (int*)carve(4096);                        // tree barrier area
    __half*        h2       = (__half*)h1;   // h1 dead after agg1; N x 40 fp16 fits

    // Persistent-kernel grid: min(jobs, co-resident capacity). Capacity from
    // the occupancy API so the grid_barrier's co-residency assumption holds.
    static int gridB = 0;
    if (gridB == 0) {
        int mb = 0;
        if (hipOccupancyMaxActiveBlocksPerMultiprocessor(&mb, build_kernel, 256, 0) != hipSuccess || mb < 1)
            mb = 2;   // conservative fallback (LDS 69632B allows 2)
        int ncu = 0;
        if (hipDeviceGetAttribute(&ncu, hipDeviceAttributeMultiprocessorCount, 0) != hipSuccess || ncu < 1)
            ncu = 256;
        long cap  = (long)mb * ncu;
        long want = (long)nbk + nbt;   // 587: offsets || gemm all-parallel
        gridB = (int)(cap < want ? cap : want);
    }

    (void)hipMemsetAsync(bar, 0, 4096, stream);
    build_kernel<<<gridB, 256, 0, stream>>>(x, ei, W1, E, N, nchunks, nbk, nbt,
                                            histT, tot, bkt, adj, rowstart, dinv,
                                            h1, bar);
    agg1_kernel<<<(N + 3) / 4, 256, 0, stream>>>(h1, rowstart, adj, dinv, x, b1, z, N);
    gemm2_mfma<<<nbt, 256, 0, stream>>>(z, W2, h2, N);
    agg2_kernel<<<(N + 3) / 4, 256, 0, stream>>>(h2, rowstart, adj, dinv, b2, y, N);
}

// Round 6
// 194.774 us; speedup vs baseline: 2.3586x; 1.0102x over previous
//
#include <hip/hip_runtime.h>
#include <hip/hip_fp16.h>

// 2-layer GCN, pull-based CSR aggregation. fp32 math; h1 fp8-e4m3, z/h2 fp16.
// R21: gemm1 A-operand streamed from global (no Xs LDS tile). R20 post-mortem:
// tree barrier worked (120->59us) but 69632B smem capped the WHOLE persistent
// kernel at 2 blocks/CU (Occupancy 18%), strangling the latency-bound P0/P2/P3
// phases. A-fragments are just 8 consecutive fp32 of an x row -> load per-lane
// float4 x2 + scalar RNE cvt (bit-identical to staged path). LDS now Wt-only
// 34816B -> 4 blocks/CU (launch_bounds(256,4)), grid 512->587 (all P1 jobs
// parallel). Epilogue = two 64-row half-tiles (33792B fits).
// R20: tree barrier (32 cells + root + release line). R19: cross-phase data
// via relaxed agent atomics, fenceless barrier. R16: fusion. R15: LDS
// counting-sort scatter. R10: stride-132 epilogue. R5/R6: no global atomics.

#define FDIM 128
#define CHUNK 2048   // edges per chunk; nchunks = ceil(E/CHUNK) must be <= 512
#define NCELL 32     // barrier arrival cells (64B apart)

using half8   = __attribute__((ext_vector_type(8))) _Float16;
using float4v = __attribute__((ext_vector_type(4))) float;
using float2v = __attribute__((ext_vector_type(2))) float;

__device__ __forceinline__ float2v fp8x2_to_f32x2(unsigned short hv) {
    return __builtin_amdgcn_cvt_pk_f32_fp8((int)hv, false);
}

__device__ __forceinline__ void a_store(int* p, int v) {
    __hip_atomic_store(p, v, __ATOMIC_RELAXED, __HIP_MEMORY_SCOPE_AGENT);
}
__device__ __forceinline__ int a_load(const int* p) {
    return __hip_atomic_load(p, __ATOMIC_RELAXED, __HIP_MEMORY_SCOPE_AGENT);
}
__device__ __forceinline__ void a_storeu(unsigned* p, unsigned v) {
    __hip_atomic_store(p, v, __ATOMIC_RELAXED, __HIP_MEMORY_SCOPE_AGENT);
}
__device__ __forceinline__ unsigned a_loadu(const unsigned* p) {
    return __hip_atomic_load(p, __ATOMIC_RELAXED, __HIP_MEMORY_SCOPE_AGENT);
}

// Tree grid-barrier (co-resident occupancy-sized grid), fenceless (all
// cross-phase data moves via agent-scope atomics at the L3 coherence point;
// __syncthreads drains vmcnt so stores are acked before arrival).
// Cells at [cell*16] (64B apart), root at [NCELL*16], release at [NCELL*16+16].
// Cumulative targets: no resets -> no races. Release is stored only after all
// blocks' arrival RMWs, i.e. after all their data stores reached L3.
__device__ __forceinline__ void grid_barrier(int* barArea, int nb, int phase) {
    __syncthreads();
    if (threadIdx.x == 0) {
        const int cell  = blockIdx.x & (NCELL - 1);
        int* cellp = barArea + cell * 16;
        int* rootp = barArea + NCELL * 16;
        int* relp  = barArea + NCELL * 16 + 16;
        const int ccnt  = (nb >> 5) + ((cell < (nb & (NCELL - 1))) ? 1 : 0);
        const int nused = (nb < NCELL) ? nb : NCELL;
        int old = __hip_atomic_fetch_add(cellp, 1, __ATOMIC_RELAXED, __HIP_MEMORY_SCOPE_AGENT);
        if (old == phase * ccnt - 1) {
            int rold = __hip_atomic_fetch_add(rootp, 1, __ATOMIC_RELAXED, __HIP_MEMORY_SCOPE_AGENT);
            if (rold == phase * nused - 1)
                a_store(relp, phase);
        }
        while (a_load(relp) < phase)
            __builtin_amdgcn_s_sleep(4);
    }
    __syncthreads();
}

// Phases:
//  P0: per-chunk dst histogram (nchunks jobs)
//  P1: per-bucket chunk-offset scan (nbk jobs)  ||  gemm1 MFMA tiles (nbt jobs)
//  P2: scatter with LDS counting sort (nchunks jobs)
//  P3: CSR finalize per bucket (nbk jobs)
__launch_bounds__(256, 4)
__global__ void build_kernel(const float* __restrict__ x, const int* __restrict__ ei,
                             const float* __restrict__ W1,
                             int E, int N, int nchunks, int nbk, int nbt,
                             int* __restrict__ histT, int* __restrict__ tot,
                             unsigned* __restrict__ bkt, int* __restrict__ adj,
                             int* __restrict__ rowstart, float* __restrict__ dinv,
                             unsigned char* __restrict__ h1, int* __restrict__ bar) {
    __shared__ __align__(16) unsigned char smem[34816];
    const int nb = gridDim.x;
    const int t  = threadIdx.x;

    // ---------------- P0: per-chunk histogram ------------------------------
    for (int j = blockIdx.x; j < nchunks; j += nb) {
        int* hist = (int*)smem;
        __syncthreads();
        hist[t] = 0;
        __syncthreads();
        const int* dst = ei + E;
        int base = j * CHUNK;
#pragma unroll
        for (int k = 0; k < CHUNK / 256; ++k) {
            int e = base + k * 256 + t;
            if (e < E) atomicAdd(&hist[dst[e] >> 8], 1);
        }
        __syncthreads();
        if (t < nbk) a_store(&histT[t * nchunks + j], hist[t]);
    }
    grid_barrier(bar, nb, 1);

    // ---------------- P1: offsets scan || gemm1 ----------------------------
    for (int j = blockIdx.x; j < nbk + nbt; j += nb) {
        if (j < nbk) {
            // exclusive scan of <=512 chunk counts; 2 slots/thread Hillis-Steele
            int* s = (int*)smem;
            __syncthreads();
            int* row = histT + (size_t)j * nchunks;
            int v0 = (t < nchunks) ? a_load(&row[t]) : 0;
            int v1 = (t + 256 < nchunks) ? a_load(&row[t + 256]) : 0;
            s[t] = v0;
            s[t + 256] = v1;
            __syncthreads();
            for (int off = 1; off < 512; off <<= 1) {
                int a  = (t >= off) ? s[t - off] : 0;
                int b2 = s[t + 256 - off];   // t+256 >= off always (off<=256)
                __syncthreads();
                s[t] += a;
                s[t + 256] += b2;
                __syncthreads();
            }
            if (t < nchunks) a_store(&row[t], s[t] - v0);           // local excl offset
            if (t + 256 < nchunks) a_store(&row[t + 256], s[t + 256] - v1);
            if (t == 255) a_store(&tot[j], s[511]);                 // bucket total
        } else {
            // ---- gemm1 tile: h1 = fp8(fp16(x) @ fp16(W1)), A streamed ----
            int tile = j - nbk;
            __syncthreads();   // guard smem reuse across jobs
            _Float16* Wt = (_Float16*)smem;   // 128 x 136 fp16 = 34816 B
            int i0 = tile * 128;
            for (int p = t; p < 128 * 128; p += 256) {
                int k = p >> 7;
                int n = p & 127;
                Wt[n * 136 + k] = (_Float16)W1[k * 128 + n];
            }
            __syncthreads();

            int lane = t & 63, w = t >> 6;
            int c = lane & 15, q = lane >> 4;
            int m0 = w * 32;

            float4v acc[2][8];
#pragma unroll
            for (int r = 0; r < 2; ++r)
#pragma unroll
                for (int nt = 0; nt < 8; ++nt) acc[r][nt] = (float4v)(0.f);

            int r0 = i0 + m0 + c;
            int r1 = r0 + 16;
            const float* xr0 = x + (size_t)r0 * FDIM;
            const float* xr1 = x + (size_t)r1 * FDIM;
#pragma unroll
            for (int kk = 0; kk < 4; ++kk) {
                int k0 = kk * 32 + q * 8;
                float4 xa = make_float4(0.f, 0.f, 0.f, 0.f), xb = xa, xc = xa, xd = xa;
                if (r0 < N) {
                    xa = *(const float4*)(xr0 + k0);
                    xb = *(const float4*)(xr0 + k0 + 4);
                }
                if (r1 < N) {
                    xc = *(const float4*)(xr1 + k0);
                    xd = *(const float4*)(xr1 + k0 + 4);
                }
                half8 a0, a1;
                a0[0] = (_Float16)xa.x; a0[1] = (_Float16)xa.y;
                a0[2] = (_Float16)xa.z; a0[3] = (_Float16)xa.w;
                a0[4] = (_Float16)xb.x; a0[5] = (_Float16)xb.y;
                a0[6] = (_Float16)xb.z; a0[7] = (_Float16)xb.w;
                a1[0] = (_Float16)xc.x; a1[1] = (_Float16)xc.y;
                a1[2] = (_Float16)xc.z; a1[3] = (_Float16)xc.w;
                a1[4] = (_Float16)xd.x; a1[5] = (_Float16)xd.y;
                a1[6] = (_Float16)xd.z; a1[7] = (_Float16)xd.w;
#pragma unroll
                for (int nt = 0; nt < 8; ++nt) {
                    half8 bv = *(const half8*)&Wt[(nt * 16 + c) * 136 + k0];
                    acc[0][nt] = __builtin_amdgcn_mfma_f32_16x16x32_f16(a0, bv, acc[0][nt], 0, 0, 0);
                    acc[1][nt] = __builtin_amdgcn_mfma_f32_16x16x32_f16(a1, bv, acc[1][nt], 0, 0, 0);
                }
            }
            // epilogue in two 64-row half-tiles: T[64][132] fp32 = 33792 B fits
            float* T = (float*)smem;
#pragma unroll
            for (int half = 0; half < 2; ++half) {
                __syncthreads();   // Wt (half 0) / prev T readers (half 1) done
                if ((w >> 1) == half) {
#pragma unroll
                    for (int r = 0; r < 2; ++r)
#pragma unroll
                        for (int reg = 0; reg < 4; ++reg) {
                            int rl = (m0 & 63) + r * 16 + q * 4 + reg;
#pragma unroll
                            for (int nt = 0; nt < 8; ++nt)
                                T[rl * 132 + nt * 16 + c] = acc[r][nt][reg];
                        }
                }
                __syncthreads();
                for (int p = t; p < 64 * 32; p += 256) {
                    int row = p >> 5;
                    int col4 = (p & 31) * 4;
                    int grow = i0 + half * 64 + row;
                    if (grow < N) {
                        const float* src = &T[row * 132 + col4];
                        int lo = __builtin_amdgcn_cvt_pk_fp8_f32(src[0], src[1], 0, false);
                        int hi = __builtin_amdgcn_cvt_pk_fp8_f32(src[2], src[3], 0, false);
                        unsigned word = ((unsigned)lo & 0xFFFFu) | (((unsigned)hi & 0xFFFFu) << 16);
                        *(unsigned*)(h1 + (size_t)grow * 128 + col4) = word;  // next-kernel consumer
                    }
                }
            }
        }
    }
    grid_barrier(bar, nb, 2);

    // ---------------- P2: scatter with in-LDS counting sort ----------------
    for (int j = blockIdx.x; j < nchunks; j += nb) {
        int* s        = (int*)smem;               // 256 ints
        int* delta    = (int*)(smem + 1024);      // 256 ints
        int* lcur     = (int*)(smem + 2048);      // 256 ints
        unsigned* buf = (unsigned*)(smem + 3072); // 2048 u32
        int* dst32    = (int*)(smem + 11264);     // 2048 ints
        __syncthreads();
        int v = (t < nbk) ? a_load(&tot[t]) : 0;
        s[t] = v;
        __syncthreads();
        for (int off = 1; off < 256; off <<= 1) {
            int tv = (t >= off) ? s[t - off] : 0;
            __syncthreads();
            s[t] += tv;
            __syncthreads();
        }
        int gbase = 0, lcnt = 0;
        if (t < nbk) {
            int cur_off = a_load(&histT[t * nchunks + j]);
            gbase = (s[t] - v) + cur_off;
            int nxt_off = (j + 1 < nchunks) ? a_load(&histT[t * nchunks + j + 1]) : v;
            lcnt = nxt_off - cur_off;
        }
        __syncthreads();
        s[t] = lcnt;
        __syncthreads();
        for (int off = 1; off < 256; off <<= 1) {
            int tv = (t >= off) ? s[t - off] : 0;
            __syncthreads();
            s[t] += tv;
            __syncthreads();
        }
        int lofs = s[t] - lcnt;
        lcur[t] = lofs;
        delta[t] = gbase - lofs;
        __syncthreads();

        int base = j * CHUNK;
#pragma unroll
        for (int k = 0; k < CHUNK / 256; ++k) {
            int e = base + k * 256 + t;
            if (e < E) {
                int src = ei[e];
                int d = ei[E + e];
                int b = d >> 8;
                int pos = atomicAdd(&lcur[b], 1);   // LDS atomic
                buf[pos] = ((unsigned)(d & 255) << 24) | (unsigned)src;
                dst32[pos] = delta[b] + pos;
            }
        }
        __syncthreads();
        int cnt = min(CHUNK, E - base);
        for (int p = t; p < cnt; p += 256)
            a_storeu(&bkt[dst32[p]], buf[p]);
    }
    grid_barrier(bar, nb, 3);

    // ---------------- P3: CSR finalize per bucket --------------------------
    for (int j = blockIdx.x; j < nbk; j += nb) {
        int* sbuf = (int*)smem;
        int* hist = (int*)(smem + 1024);
        int* cur  = (int*)(smem + 2048);
        __syncthreads();
        int v = (t < nbk) ? a_load(&tot[t]) : 0;
        sbuf[t] = v;
        __syncthreads();
        for (int off = 1; off < 256; off <<= 1) {
            int tv = (t >= off) ? sbuf[t - off] : 0;
            __syncthreads();
            sbuf[t] += tv;
            __syncthreads();
        }
        int bb = sbuf[j] - a_load(&tot[j]);
        int nb_ = a_load(&tot[j]);
        __syncthreads();
        hist[t] = 0;
        __syncthreads();
        const unsigned* bk = bkt + bb;
        for (int e = t; e < nb_; e += 256) atomicAdd(&hist[a_loadu(&bk[e]) >> 24], 1);
        __syncthreads();
        int h_t = hist[t];
        sbuf[t] = h_t;
        __syncthreads();
        for (int off = 1; off < 256; off <<= 1) {
            int vv = (t >= off) ? sbuf[t - off] : 0;
            __syncthreads();
            sbuf[t] += vv;
            __syncthreads();
        }
        int excl_t = sbuf[t] - h_t;
        int node = j * 256 + t;
        if (node < N) {
            rowstart[node] = bb + excl_t;              // next-kernel consumer
            dinv[node] = rsqrtf((float)(h_t + 1));     // +1 self-loop
        }
        if (j == 0 && t == 0) rowstart[N] = E;
        cur[t] = excl_t;
        __syncthreads();
        for (int e = t; e < nb_; e += 256) {
            unsigned vv = a_loadu(&bk[e]);
            int pos = atomicAdd(&cur[vv >> 24], 1);    // LDS atomic
            adj[bb + pos] = (int)(vv & 0xFFFFFFu);     // src < 2^24; next-kernel consumer
        }
    }
}

// z[i,:] = relu( dinv[i]*(sum_s h1[s,:]*dinv[s] + h1[i,:]*dinv[i]) + b1 ) + x[i,:]
// h1 fp8-e4m3, 128 B/row; lane = 2 feats; 8 gathers in flight. (R13 form.)
__global__ void agg1_kernel(const unsigned char* __restrict__ h1, const int* __restrict__ rowstart,
                            const int* __restrict__ adj, const float* __restrict__ dinv,
                            const float* __restrict__ x, const float* __restrict__ b1,
                            __half* __restrict__ z, int N) {
    int wave = threadIdx.x >> 6;
    int lane = threadIdx.x & 63;
    int i = blockIdx.x * 4 + wave;
    if (i >= N) return;
    int s0 = rowstart[i], s1 = rowstart[i + 1];
    float ax = 0.f, ay = 0.f;
    int n = s0;
    for (; n + 7 < s1; n += 8) {
        int s[8];
        float w[8];
        unsigned short hv[8];
#pragma unroll
        for (int q = 0; q < 8; ++q) s[q] = adj[n + q];
#pragma unroll
        for (int q = 0; q < 8; ++q) w[q] = dinv[s[q]];
#pragma unroll
        for (int q = 0; q < 8; ++q)
            hv[q] = *(const unsigned short*)(h1 + (size_t)s[q] * 128 + lane * 2);
#pragma unroll
        for (int q = 0; q < 8; ++q) {
            float2v f = fp8x2_to_f32x2(hv[q]);
            ax += f.x * w[q];
            ay += f.y * w[q];
        }
    }
    if (n + 3 < s1) {
        int s[4];
        float w[4];
        unsigned short hv[4];
#pragma unroll
        for (int q = 0; q < 4; ++q) s[q] = adj[n + q];
#pragma unroll
        for (int q = 0; q < 4; ++q) w[q] = dinv[s[q]];
#pragma unroll
        for (int q = 0; q < 4; ++q)
            hv[q] = *(const unsigned short*)(h1 + (size_t)s[q] * 128 + lane * 2);
#pragma unroll
        for (int q = 0; q < 4; ++q) {
            float2v f = fp8x2_to_f32x2(hv[q]);
            ax += f.x * w[q];
            ay += f.y * w[q];
        }
        n += 4;
    }
    for (; n < s1; ++n) {
        int sa = adj[n];
        float wa = dinv[sa];
        float2v f = fp8x2_to_f32x2(*(const unsigned short*)(h1 + (size_t)sa * 128 + lane * 2));
        ax += f.x * wa;
        ay += f.y * wa;
    }
    float di = dinv[i];
    float self = di * di;
    float2v hi = fp8x2_to_f32x2(*(const unsigned short*)(h1 + (size_t)i * 128 + lane * 2));
    ax = ax * di + hi.x * self;
    ay = ay * di + hi.y * self;
    float2 bb = ((const float2*)b1)[lane];
    float2 xi = ((const float2*)(x + (size_t)i * FDIM))[lane];
    float rx = fmaxf(ax + bb.x, 0.f) + xi.x;
    float ry = fmaxf(ay + bb.y, 0.f) + xi.y;
    ((__half2*)(z + (size_t)i * FDIM))[lane] = __floats2half2_rn(rx, ry);
}

// ---- MFMA GEMM2: h2 = z @ fp16(W2), fp32 accum, fp16 out (stride 40) ----
__launch_bounds__(256, 2)
__global__ void gemm2_mfma(const __half* __restrict__ z, const float* __restrict__ W2,
                           __half* __restrict__ h2, int N) {
    __shared__ __align__(16) unsigned char smem[49152];
    _Float16* Zs  = (_Float16*)smem;                 // 128*136*2 = 34816 B
    _Float16* W2t = (_Float16*)(smem + 34816);       // 48*136*2  = 13056 B
    int t = threadIdx.x;
    int i0 = blockIdx.x * 128;

    for (int p = t; p < 128 * 16; p += 256) {
        int row = p >> 4;
        int ck = (p & 15) * 8;
        int grow = i0 + row;
        half8 v = (half8)(_Float16)0;
        if (grow < N) v = *(const half8*)(z + (size_t)grow * FDIM + ck);
        *(half8*)&Zs[row * 136 + ck] = v;
    }
    for (int p = t; p < 48 * 128; p += 256) {
        int n = p >> 7;
        int k = p & 127;
        W2t[n * 136 + k] = (n < 40) ? (_Float16)W2[k * 40 + n] : (_Float16)0;
    }
    __syncthreads();

    int lane = t & 63, w = t >> 6;
    int c = lane & 15, q = lane >> 4;
    int m0 = w * 32;

    float4v acc[2][3];
#pragma unroll
    for (int r = 0; r < 2; ++r)
#pragma unroll
        for (int nt = 0; nt < 3; ++nt) acc[r][nt] = (float4v)(0.f);

#pragma unroll
    for (int kk = 0; kk < 4; ++kk) {
        int k0 = kk * 32 + q * 8;
        half8 a0 = *(const half8*)&Zs[(m0 + c) * 136 + k0];
        half8 a1 = *(const half8*)&Zs[(m0 + 16 + c) * 136 + k0];
#pragma unroll
        for (int nt = 0; nt < 3; ++nt) {
            half8 bv = *(const half8*)&W2t[(nt * 16 + c) * 136 + k0];
            acc[0][nt] = __builtin_amdgcn_mfma_f32_16x16x32_f16(a0, bv, acc[0][nt], 0, 0, 0);
            acc[1][nt] = __builtin_amdgcn_mfma_f32_16x16x32_f16(a1, bv, acc[1][nt], 0, 0, 0);
        }
    }
    __syncthreads();   // Zs/W2t dead; reuse smem as fp16 tile T[128][58]
    _Float16* T = (_Float16*)smem;
#pragma unroll
    for (int r = 0; r < 2; ++r)
#pragma unroll
        for (int reg = 0; reg < 4; ++reg) {
            int rl = m0 + r * 16 + q * 4 + reg;
#pragma unroll
            for (int nt = 0; nt < 3; ++nt)
                T[rl * 58 + nt * 16 + c] = (_Float16)acc[r][nt][reg];
        }
    __syncthreads();
    for (int p = t; p < 128 * 20; p += 256) {
        int row = p / 20;
        int c2 = p % 20;
        int grow = i0 + row;
        if (grow < N)
            *(__half2*)(h2 + (size_t)grow * 40 + c2 * 2) =
                *(const __half2*)&T[row * 58 + c2 * 2];
    }
}

// y[i,:] = dinv[i]*(sum_s h2[s,:]*dinv[s] + h2[i,:]*dinv[i]) + b2
__global__ void agg2_kernel(const __half* __restrict__ h2, const int* __restrict__ rowstart,
                            const int* __restrict__ adj, const float* __restrict__ dinv,
                            const float* __restrict__ b2, float* __restrict__ y, int N) {
    int wave = threadIdx.x >> 6;
    int lane = threadIdx.x & 63;
    int i = blockIdx.x * 4 + wave;
    if (i >= N) return;
    int e = (lane >= 40) ? 2 : ((lane >= 20) ? 1 : 0);
    int f = lane - 20 * e;
    int s0 = rowstart[i], s1 = rowstart[i + 1];
    float ax = 0.f, ay = 0.f;
    if (lane < 60) {
        int n = s0 + e;
        for (; n + 9 < s1; n += 12) {
            int s[4];
            float w[4];
            float2 r[4];
#pragma unroll
            for (int q = 0; q < 4; ++q) s[q] = adj[n + 3 * q];
#pragma unroll
            for (int q = 0; q < 4; ++q) w[q] = dinv[s[q]];
#pragma unroll
            for (int q = 0; q < 4; ++q)
                r[q] = __half22float2(((const __half2*)(h2 + (size_t)s[q] * 40))[f]);
#pragma unroll
            for (int q = 0; q < 4; ++q) {
                ax += r[q].x * w[q];
                ay += r[q].y * w[q];
            }
        }
        for (; n < s1; n += 3) {
            int sa = adj[n];
            float wa = dinv[sa];
            float2 ra = __half22float2(((const __half2*)(h2 + (size_t)sa * 40))[f]);
            ax += ra.x * wa;
            ay += ra.y * wa;
        }
    }
    float sx = ax + __shfl(ax, lane + 20, 64) + __shfl(ax, lane + 40, 64);
    float sy = ay + __shfl(ay, lane + 20, 64) + __shfl(ay, lane + 40, 64);
    if (lane < 20) {
        float di = dinv[i];
        float2 hi = __half22float2(((const __half2*)(h2 + (size_t)i * 40))[lane]);
        float2 bb = ((const float2*)b2)[lane];
        float2 res;
        res.x = sx * di + hi.x * di * di + bb.x;
        res.y = sy * di + hi.y * di * di + bb.y;
        ((float2*)(y + (size_t)i * 40))[lane] = res;
    }
}

extern "C" void kernel_launch(void* const* d_in, const int* in_sizes, int n_in,
                              void* d_out, int out_size, void* d_ws, size_t ws_size,
                              hipStream_t stream) {
    const float* x  = (const float*)d_in[0];
    const int*   ei = (const int*)d_in[1];
    const float* W1 = (const float*)d_in[2];
    const float* b1 = (const float*)d_in[3];
    const float* W2 = (const float*)d_in[4];
    const float* b2 = (const float*)d_in[5];
    float* y = (float*)d_out;

    const int H = in_sizes[3];           // 128
    const int F = in_sizes[2] / H;       // 128
    const int N = in_sizes[0] / F;       // 50000
    const int E = in_sizes[1] / 2;       // 800000
    (void)H; (void)ws_size; (void)n_in; (void)out_size;

    const int nbk = (N + 255) >> 8;              // 196 buckets (<=256)
    const int nchunks = (E + CHUNK - 1) / CHUNK; // 391 (<=512)
    const int nbt = (N + 127) / 128;             // 391 gemm tiles

    size_t off = 0;
    auto carve = [&](size_t bytes) -> void* {
        void* p = (char*)d_ws + off;
        off += (bytes + 255) & ~(size_t)255;
        return p;
    };
    int*           histT    = (int*)carve((size_t)nbk * nchunks * 4);
    int*           tot      = (int*)carve((size_t)nbk * 4);
    unsigned*      bkt      = (unsigned*)carve((size_t)E * 4);
    int*           rowstart = (int*)carve((size_t)(N + 1) * 4);
    float*         dinv     = (float*)carve((size_t)N * 4);
    int*           adj      = (int*)carve((size_t)E * 4);
    unsigned char* h1       = (unsigned char*)carve((size_t)N * 128);   // fp8 e4m3
    __half*        z        = (__half*)carve((size_t)N * FDIM * 2);
    int*           bar      = (int*)carve(4096);                        // tree barrier area
    __half*        h2       = (__half*)h1;   // h1 dead after agg1; N x 40 fp16 fits

    // Persistent-kernel grid: min(jobs, co-resident capacity). Capacity from
    // the occupancy API so the grid_barrier's co-residency assumption holds.
    static int gridB = 0;
    if (gridB == 0) {
        int mb = 0;
        if (hipOccupancyMaxActiveBlocksPerMultiprocessor(&mb, build_kernel, 256, 0) != hipSuccess || mb < 1)
            mb = 2;   // conservative fallback
        int ncu = 0;
        if (hipDeviceGetAttribute(&ncu, hipDeviceAttributeMultiprocessorCount, 0) != hipSuccess || ncu < 1)
            ncu = 256;
        long cap  = (long)mb * ncu;
        long want = (long)nbk + nbt;   // 587: offsets || gemm all-parallel
        gridB = (int)(cap < want ? cap : want);
    }

    (void)hipMemsetAsync(bar, 0, 4096, stream);
    build_kernel<<<gridB, 256, 0, stream>>>(x, ei, W1, E, N, nchunks, nbk, nbt,
                                            histT, tot, bkt, adj, rowstart, dinv,
                                            h1, bar);
    agg1_kernel<<<(N + 3) / 4, 256, 0, stream>>>(h1, rowstart, adj, dinv, x, b1, z, N);
    gemm2_mfma<<<nbt, 256, 0, stream>>>(z, W2, h2, N);
    agg2_kernel<<<(N + 3) / 4, 256, 0, stream>>>(h2, rowstart, adj, dinv, b2, y, N);
}